// Round 1
// baseline (2213.679 us; speedup 1.0000x reference)
//
#include <hip/hip_runtime.h>
#include <math.h>

// ---------------- problem constants ----------------
constexpr int NSWEEP = 8;

// ws offsets (in floats)
constexpr size_t OFF_SUMX   = 0;        // 22
constexpr size_t OFF_G      = 22;       // 253
constexpr size_t OFF_SUM2   = 288;      // 20
constexpr size_t OFF_SUMSQ2 = 308;      // 20
constexpr size_t OFF_S2     = 328;      // 20
constexpr size_t OFF_A      = 352;      // 484
constexpr size_t OFF_D      = 840;      // 22
constexpr size_t OFF_WR     = 864;      // 5280 -> 6144
constexpr size_t OFF_COV    = 6144;     // 8192*400 -> 3282944 (later reused as `mixed` 8192*324)
constexpr size_t OFF_LQKV   = 3282944;  // 8192*3*324 -> 11245568
constexpr size_t OFF_FEAT   = 11245568; // 1024*1368 -> 12646400 floats = 50.6 MB

// ---------------- constexpr tables ----------------
struct Tri { int a[253]; int b[253]; };
constexpr Tri mk_tri(int n) {
    Tri t{}; int c = 0;
    for (int i = 0; i < n; ++i) for (int j = i; j < n; ++j) { t.a[c] = i; t.b[c] = j; ++c; }
    return t;
}
constexpr Tri T22 = mk_tri(22);  // 253 pairs
constexpr Tri T20 = mk_tri(20);  // 210 pairs
constexpr Tri T18 = mk_tri(18);  // 171 pairs

// round-robin (circle method) schedule for n=18: 17 rounds x 9 disjoint pairs, p<q
struct Sched { int p[17][9]; int q[17][9]; };
constexpr Sched mk_sched() {
    Sched s{};
    for (int r = 0; r < 17; ++r)
        for (int k = 0; k < 9; ++k) {
            int x, y;
            if (k == 0) { x = 17; y = r; }
            else { x = (r + k) % 17; y = (r - k + 17) % 17; }
            s.p[r][k] = x < y ? x : y;
            s.q[r][k] = x < y ? y : x;
        }
    return s;
}
constexpr Sched SCH = mk_sched();

// ---------------- wave-parallel 18x18 Jacobi eigh ----------------
// Lane layout: lane = base + jj holds column jj (a[i] = A[i][jj]) of its matrix.
// 3 matrices per wave (bases 0,18,36); lanes 54..63 run a harmless duplicate.
__device__ __forceinline__ void jacobi18(float* __restrict__ a, float* __restrict__ v,
                                         int jj, int base) {
    for (int sw = 0; sw < NSWEEP; ++sw) {
#pragma unroll
        for (int r = 0; r < 17; ++r) {
            float cc[9], ss[9];
#pragma unroll
            for (int k = 0; k < 9; ++k) {
                const int p = SCH.p[r][k], q = SCH.q[r][k];
                float app = __shfl(a[p], base + p, 64);
                float aqq = __shfl(a[q], base + q, 64);
                float apq = __shfl(a[q], base + p, 64);
                float apqc = (fabsf(apq) < 1e-36f) ? 1e-36f : apq;
                float tau = (aqq - app) * 0.5f * __builtin_amdgcn_rcpf(apqc);
                float t = __builtin_amdgcn_rcpf(fabsf(tau) + __builtin_amdgcn_sqrtf(1.f + tau * tau));
                t = (tau < 0.f) ? -t : t;
                float c = __builtin_amdgcn_rsqf(1.f + t * t);
                float s = t * c;
                cc[k] = c; ss[k] = s;
            }
            // row update (lane-local registers), all 9 disjoint pairs
#pragma unroll
            for (int k = 0; k < 9; ++k) {
                const int p = SCH.p[r][k], q = SCH.q[r][k];
                float tp = a[p], tq = a[q];
                a[p] = cc[k] * tp - ss[k] * tq;
                a[q] = ss[k] * tp + cc[k] * tq;
            }
            // this lane's pair id + partner (inverse of circle method)
            int k1 = jj - r; if (k1 < 0) k1 += 17;
            int kk, partner;
            if (jj == 17)      { kk = 0;        partner = r; }
            else if (k1 == 0)  { kk = 0;        partner = 17; }
            else if (k1 <= 8)  { kk = k1;       partner = r - k1; if (partner < 0) partner += 17; }
            else               { kk = 17 - k1;  partner = r + 17 - k1; if (partner >= 17) partner -= 17; }
            float mc = cc[0], ms = ss[0];
#pragma unroll
            for (int t2 = 1; t2 < 9; ++t2) { if (kk == t2) { mc = cc[t2]; ms = ss[t2]; } }
            float ssig = (jj < partner) ? -ms : ms;
            int paddr = base + partner;
            // column update on A and V via partner exchange
#pragma unroll
            for (int i = 0; i < 18; ++i) {
                float oa = __shfl(a[i], paddr, 64);
                a[i] = mc * a[i] + ssig * oa;
            }
#pragma unroll
            for (int i = 0; i < 18; ++i) {
                float ov = __shfl(v[i], paddr, 64);
                v[i] = mc * v[i] + ssig * ov;
            }
        }
    }
}

// ---------------- K0: zero atomic accumulators ----------------
__global__ void k0_zero(float* ws) {
    int tid = threadIdx.x;
    for (int i = tid; i < 352; i += 256) ws[i] = 0.f;
}

// ---------------- K1: x channel sums + Gram (for analytic BN1) ----------------
__global__ __launch_bounds__(256) void k1_stats(const float* __restrict__ x,
                                                float* __restrict__ sumx,
                                                float* __restrict__ G) {
    int b = blockIdx.x, tid = threadIdx.x;
    __shared__ float xt[22 * 257];
    float accp = 0.f, accs = 0.f;
    int c1 = 0, c2 = 0;
    if (tid < 253) { c1 = T22.a[tid]; c2 = T22.b[tid]; }
    const float* xb = x + (size_t)b * 22 * 2047;
    for (int t0 = 0; t0 < 2047; t0 += 256) {
        __syncthreads();
        for (int idx = tid; idx < 22 * 256; idx += 256) {
            int c = idx >> 8, tl = idx & 255;
            int t = t0 + tl;
            xt[c * 257 + tl] = (t < 2047) ? xb[c * 2047 + t] : 0.f;
        }
        __syncthreads();
        if (tid < 253) {
            float s = 0.f;
            for (int t = 0; t < 256; ++t) s += xt[c1 * 257 + t] * xt[c2 * 257 + t];
            accp += s;
        }
        if (tid < 22) {
            float s = 0.f;
            for (int t = 0; t < 256; ++t) s += xt[tid * 257 + t];
            accs += s;
        }
    }
    if (tid < 253) atomicAdd(&G[tid], accp);
    if (tid < 22) atomicAdd(&sumx[tid], accs);
}

// ---------------- K2: finalize BN1 -> A = diag(s1)W, d; reorder w_temp ----------------
__global__ __launch_bounds__(256) void k2_prep(const float* __restrict__ w_spat,
                                               const float* __restrict__ b_spat,
                                               const float* __restrict__ g1,
                                               const float* __restrict__ be1,
                                               const float* __restrict__ w_temp,
                                               const float* __restrict__ sumx,
                                               const float* __restrict__ G,
                                               float* __restrict__ A,
                                               float* __restrict__ dv,
                                               float* __restrict__ w_r) {
    int tid = threadIdx.x;
    __shared__ float cov[22 * 22], mux[22], mu1s[22], s1s[22];
    const float invN = 1.f / (1024.f * 2047.f);
    if (tid < 22) mux[tid] = sumx[tid] * invN;
    __syncthreads();
    if (tid < 253) {
        int c1 = T22.a[tid], c2 = T22.b[tid];
        float cv = G[tid] * invN - mux[c1] * mux[c2];
        cov[c1 * 22 + c2] = cv; cov[c2 * 22 + c1] = cv;
    }
    __syncthreads();
    if (tid < 22) {
        int c = tid;
        float m = b_spat[c], varv = 0.f;
        for (int e = 0; e < 22; ++e) m += w_spat[c * 22 + e] * mux[e];
        for (int i = 0; i < 22; ++i) {
            float wi = w_spat[c * 22 + i];
            for (int j = 0; j < 22; ++j) varv += wi * w_spat[c * 22 + j] * cov[i * 22 + j];
        }
        mu1s[c] = m;
        s1s[c] = g1[c] * rsqrtf(varv + 1e-5f);
    }
    __syncthreads();
    for (int idx = tid; idx < 484; idx += 256) {
        int c = idx / 22;
        A[idx] = s1s[c] * w_spat[idx];
    }
    if (tid < 22) dv[tid] = s1s[tid] * (b_spat[tid] - mu1s[tid]) + be1[tid];
    // w_r[(c*12+k)*20 + f] = w_temp[f][c][k]
    for (int idx = tid; idx < 5280; idx += 256) {
        int f = idx / 264, r = idx % 264;
        w_r[r * 20 + f] = w_temp[idx];
    }
}

// ---------------- K3: fused (spatial+BN1) -> temporal conv -> patch raw cov + BN2 stats ----------------
__global__ __launch_bounds__(256) void k3_conv(const float* __restrict__ x,
                                               const float* __restrict__ wsA,
                                               const float* __restrict__ wsd,
                                               const float* __restrict__ w_r,
                                               float* __restrict__ cov_raw,
                                               float* __restrict__ sum2,
                                               float* __restrict__ sumsq2) {
    int bp = blockIdx.x;           // b*8 + p
    int b = bp >> 3, p = bp & 7;
    int tid = threadIdx.x;
    __shared__ float xs[22 * 267];  // x tile, then conv-input (A x + d, zero-padded) in place
    __shared__ float h2[20 * 257];  // conv output tile (b_temp dropped: shift-invariant)
    __shared__ float pm[20];

    const float* xb = x + (size_t)b * 22 * 2047;
    const int t0 = p * 256 - 6;
    for (int idx = tid; idx < 22 * 267; idx += 256) {
        int c = idx / 267, tl = idx % 267;
        int t = t0 + tl;
        xs[idx] = (t >= 0 && t < 2047) ? xb[c * 2047 + t] : 0.f;
    }
    __syncthreads();
    // conv input in place: column per thread
    for (int tl = tid; tl < 267; tl += 256) {
        float xv[22];
#pragma unroll
        for (int c = 0; c < 22; ++c) xv[c] = xs[c * 267 + tl];
        int t = t0 + tl;
        bool valid = (t >= 0 && t < 2047);
#pragma unroll
        for (int c = 0; c < 22; ++c) {
            float acc = wsd[c];
#pragma unroll
            for (int e = 0; e < 22; ++e) acc += wsA[c * 22 + e] * xv[e];
            xs[c * 267 + tl] = valid ? acc : 0.f;
        }
    }
    __syncthreads();
    // temporal conv: thread = output column
    {
        int tl = tid;
        float acc[20];
#pragma unroll
        for (int f = 0; f < 20; ++f) acc[f] = 0.f;
        for (int c = 0; c < 22; ++c) {
#pragma unroll
            for (int k = 0; k < 12; ++k) {
                float hv = xs[c * 267 + tl + k];
                const float* wp = w_r + (c * 12 + k) * 20;   // wave-uniform -> s_load
#pragma unroll
                for (int f = 0; f < 20; ++f) acc[f] += wp[f] * hv;
            }
        }
#pragma unroll
        for (int f = 0; f < 20; ++f) h2[f * 257 + tl] = acc[f];
    }
    __syncthreads();
    // per-patch means + global BN2 accumulators
    if (tid < 20) {
        int f = tid;
        float s = 0.f, ss = 0.f;
        for (int t = 0; t < 256; ++t) { float v = h2[f * 257 + t]; s += v; ss += v * v; }
        pm[f] = s * (1.f / 256.f);
        atomicAdd(&sum2[f], s);
        atomicAdd(&sumsq2[f], ss);
    }
    __syncthreads();
    // raw patch covariance (unnormalized; trace-norm cancels divisors downstream)
    for (int pr = tid; pr < 210; pr += 256) {
        int f = T20.a[pr], g = T20.b[pr];
        float s = 0.f;
        for (int t = 0; t < 256; ++t) s += h2[f * 257 + t] * h2[g * 257 + t];
        float cv = s - 256.f * pm[f] * pm[g];
        cov_raw[(size_t)bp * 400 + f * 20 + g] = cv;
        if (f != g) cov_raw[(size_t)bp * 400 + g * 20 + f] = cv;
    }
}

// ---------------- K4: finalize BN2 scale ----------------
__global__ void k4_s2(const float* __restrict__ g2, const float* __restrict__ sum2,
                      const float* __restrict__ sumsq2, float* __restrict__ s2) {
    int tid = threadIdx.x;
    if (tid < 20) {
        const float invN = 1.f / (1024.f * 2048.f);
        float mu = sum2[tid] * invN;
        float var = sumsq2[tid] * invN - mu * mu;
        s2[tid] = g2[tid] * rsqrtf(var + 1e-5f);
    }
}

// ---------------- K5: normalize cov, BiMap Q/K/V, eigh, logm ----------------
__global__ __launch_bounds__(64) void k5_qkv(const float* __restrict__ wq,
                                             const float* __restrict__ wk,
                                             const float* __restrict__ wv,
                                             const float* __restrict__ s2g,
                                             const float* __restrict__ cov_raw,
                                             float* __restrict__ lqkv) {
    int bp = blockIdx.x;
    int lane = threadIdx.x;
    __shared__ float covn[400];
    __shared__ float Wl[1080];      // [m][18][20]
    __shared__ float Tf[1080];      // [m][18][20] = W * covn
    __shared__ float Vs[972];       // [m][18][18]
    __shared__ float lws[54];
    __shared__ float s2l[20];
    __shared__ float trinv;

    for (int idx = lane; idx < 1080; idx += 64) {
        int m = idx / 360, rem = idx % 360;
        const float* W = (m == 0) ? wq : (m == 1) ? wk : wv;
        Wl[idx] = W[rem];
    }
    if (lane < 20) s2l[lane] = s2g[lane];
    __syncthreads();
    for (int idx = lane; idx < 400; idx += 64) {
        int f = idx / 20, g = idx % 20;
        covn[idx] = s2l[f] * s2l[g] * cov_raw[(size_t)bp * 400 + idx];
    }
    __syncthreads();
    if (lane == 0) {
        float t = 0.f;
        for (int f = 0; f < 20; ++f) t += covn[f * 20 + f];
        trinv = 1.f / t;
    }
    __syncthreads();
    for (int idx = lane; idx < 400; idx += 64) covn[idx] *= trinv;
    __syncthreads();
    // T[m][i][d] = sum_e W_m[i][e] covn[e][d]
    for (int idx = lane; idx < 1080; idx += 64) {
        int m = idx / 360, rem = idx % 360, i = rem / 20, dd = rem % 20;
        float acc = 0.f;
        for (int e = 0; e < 20; ++e) acc += Wl[m * 360 + i * 20 + e] * covn[e * 20 + dd];
        Tf[idx] = acc;
    }
    __syncthreads();

    int grp = lane / 18;
    int jj = lane - grp * 18;
    int m = grp < 3 ? grp : 2;
    int base = grp * 18;   // lanes 54..63: isolated duplicate group
    float a[18], v[18];
#pragma unroll
    for (int i = 0; i < 18; ++i) {
        float acc = 0.f;
        for (int d = 0; d < 20; ++d) acc += Tf[(m * 18 + i) * 20 + d] * Wl[m * 360 + jj * 20 + d];
        a[i] = acc;
        v[i] = (i == jj) ? 1.f : 0.f;
    }
    jacobi18(a, v, jj, base);
    float lam = a[0];
#pragma unroll
    for (int i = 1; i < 18; ++i) if (jj == i) lam = a[i];
    float lw = __logf(fmaxf(lam, 1e-10f));
    if (grp < 3) {
#pragma unroll
        for (int i = 0; i < 18; ++i) Vs[(m * 18 + i) * 18 + jj] = v[i];
        lws[m * 18 + jj] = lw;
    }
    __syncthreads();
    // L = V diag(lw) V^T, write lq/lk/lv
    for (int idx = lane; idx < 972; idx += 64) {
        int m2 = idx / 324, rem = idx % 324, i = rem / 18, jo = rem % 18;
        float acc = 0.f;
#pragma unroll
        for (int kk = 0; kk < 18; ++kk)
            acc += Vs[(m2 * 18 + i) * 18 + kk] * lws[m2 * 18 + kk] * Vs[(m2 * 18 + jo) * 18 + kk];
        lqkv[(size_t)(bp * 3 + m2) * 324 + rem] = acc;
    }
}

// ---------------- K6: log-Euclidean attention -> mixed tangent matrices ----------------
__global__ __launch_bounds__(256) void k6_attn(const float* __restrict__ lqkv,
                                               float* __restrict__ mixed) {
    int b = blockIdx.x, tid = threadIdx.x;
    __shared__ float L[7776];       // [p][m][324]
    __shared__ float sq[8], sk[8], cross[64], prob[64];
    const float* src = lqkv + (size_t)b * 7776;
    for (int idx = tid; idx < 7776; idx += 256) L[idx] = src[idx];
    __syncthreads();
    if (tid < 64) {
        int i = tid >> 3, j = tid & 7;
        const float* fq = &L[(i * 3 + 0) * 324];
        const float* fk = &L[(j * 3 + 1) * 324];
        float cr = 0.f;
        for (int e = 0; e < 324; ++e) cr += fq[e] * fk[e];
        cross[tid] = cr;
    } else if (tid < 72) {
        int i = tid - 64;
        const float* fq = &L[(i * 3 + 0) * 324];
        float s = 0.f;
        for (int e = 0; e < 324; ++e) s += fq[e] * fq[e];
        sq[i] = s;
    } else if (tid < 80) {
        int i = tid - 72;
        const float* fk = &L[(i * 3 + 1) * 324];
        float s = 0.f;
        for (int e = 0; e < 324; ++e) s += fk[e] * fk[e];
        sk[i] = s;
    }
    __syncthreads();
    if (tid < 8) {
        int j = tid;
        float w[8], mx = -1e30f;
        for (int i = 0; i < 8; ++i) {
            float d2 = fmaxf(sq[i] + sk[j] - 2.f * cross[i * 8 + j], 0.f);
            float en = sqrtf(d2 + 1e-12f);
            w[i] = 1.f / (1.f + log1pf(en));
            mx = fmaxf(mx, w[i]);
        }
        float ssum = 0.f;
        for (int i = 0; i < 8; ++i) { w[i] = __expf(w[i] - mx); ssum += w[i]; }
        float inv = 1.f / ssum;
        for (int i = 0; i < 8; ++i) prob[i * 8 + j] = w[i] * inv;
    }
    __syncthreads();
    float* dst = mixed + (size_t)b * 8 * 324;
    for (int idx = tid; idx < 8 * 324; idx += 256) {
        int j = idx / 324, e = idx % 324;
        float acc = 0.f;
#pragma unroll
        for (int i = 0; i < 8; ++i) acc += prob[i * 8 + j] * L[(i * 3 + 2) * 324 + e];
        dst[idx] = acc;
    }
}

// ---------------- K7: eigh(mixed) -> clamp eigs (expm∘reeig∘logm collapsed) -> triu vec ----------------
__global__ __launch_bounds__(64) void k7_post(const float* __restrict__ mixed,
                                              float* __restrict__ feat) {
    int blk = blockIdx.x;
    int lane = threadIdx.x;
    int grp = lane / 18;
    int jj = lane - grp * 18;
    int m = grp < 3 ? grp : 2;
    int base = grp * 18;
    int mat = blk * 3 + m;                 // 0..8192 (last partial)
    int matc = mat < 8192 ? mat : 8191;
    __shared__ float Vs[972];
    __shared__ float lws[54];

    const float* src = mixed + (size_t)matc * 324;
    float a[18], v[18];
#pragma unroll
    for (int i = 0; i < 18; ++i) {
        a[i] = src[i * 18 + jj];
        v[i] = (i == jj) ? 1.f : 0.f;
    }
    jacobi18(a, v, jj, base);
    float lam = a[0];
#pragma unroll
    for (int i = 1; i < 18; ++i) if (jj == i) lam = a[i];
    float lw = fmaxf(lam, -9.210340371976182f);   // ln(1e-4): expm -> reeig -> logm collapsed
    if (grp < 3) {
#pragma unroll
        for (int i = 0; i < 18; ++i) Vs[(m * 18 + i) * 18 + jj] = v[i];
        lws[m * 18 + jj] = lw;
    }
    __syncthreads();
    for (int idx = lane; idx < 513; idx += 64) {
        int m2 = idx / 171, rem = idx % 171;
        int mat2 = blk * 3 + m2;
        if (mat2 >= 8192) continue;
        int i = T18.a[rem], jo = T18.b[rem];
        float acc = 0.f;
#pragma unroll
        for (int kk = 0; kk < 18; ++kk)
            acc += Vs[(m2 * 18 + i) * 18 + kk] * lws[m2 * 18 + kk] * Vs[(m2 * 18 + jo) * 18 + kk];
        float scl = (i == jo) ? 1.f : 1.41421356237309515f;
        int bb = mat2 >> 3, pp = mat2 & 7;
        feat[(size_t)bb * 1368 + pp * 171 + rem] = acc * scl;
    }
}

// ---------------- K8: final linear ----------------
__global__ __launch_bounds__(256) void k8_lin(const float* __restrict__ feat,
                                              const float* __restrict__ w_lin,
                                              const float* __restrict__ b_lin,
                                              float* __restrict__ out) {
    int b = blockIdx.x, tid = threadIdx.x;
    int o = tid >> 6, lane = tid & 63;
    const float* fb = feat + (size_t)b * 1368;
    const float* wo = w_lin + o * 1368;
    float acc = 0.f;
    for (int e = lane; e < 1368; e += 64) acc += fb[e] * wo[e];
    for (int off = 32; off; off >>= 1) acc += __shfl_down(acc, off, 64);
    if (lane == 0) out[b * 4 + o] = acc + b_lin[o];
}

// ---------------- launcher ----------------
extern "C" void kernel_launch(void* const* d_in, const int* in_sizes, int n_in,
                              void* d_out, int out_size, void* d_ws, size_t ws_size,
                              hipStream_t stream) {
    (void)in_sizes; (void)n_in; (void)out_size; (void)ws_size;
    const float* x      = (const float*)d_in[0];
    const float* w_spat = (const float*)d_in[1];
    const float* b_spat = (const float*)d_in[2];
    const float* g1     = (const float*)d_in[3];
    const float* be1    = (const float*)d_in[4];
    const float* w_temp = (const float*)d_in[5];
    // d_in[6] = b_temp : per-channel shift, cancels in patch covariance -> unused
    const float* g2     = (const float*)d_in[7];
    // d_in[8] = be2 : shift, cancels -> unused
    const float* wq     = (const float*)d_in[9];
    const float* wk     = (const float*)d_in[10];
    const float* wv     = (const float*)d_in[11];
    const float* w_lin  = (const float*)d_in[12];
    const float* b_lin  = (const float*)d_in[13];
    float* ws  = (float*)d_ws;
    float* out = (float*)d_out;

    k0_zero<<<1, 256, 0, stream>>>(ws);
    k1_stats<<<1024, 256, 0, stream>>>(x, ws + OFF_SUMX, ws + OFF_G);
    k2_prep<<<1, 256, 0, stream>>>(w_spat, b_spat, g1, be1, w_temp,
                                   ws + OFF_SUMX, ws + OFF_G,
                                   ws + OFF_A, ws + OFF_D, ws + OFF_WR);
    k3_conv<<<8192, 256, 0, stream>>>(x, ws + OFF_A, ws + OFF_D, ws + OFF_WR,
                                      ws + OFF_COV, ws + OFF_SUM2, ws + OFF_SUMSQ2);
    k4_s2<<<1, 64, 0, stream>>>(g2, ws + OFF_SUM2, ws + OFF_SUMSQ2, ws + OFF_S2);
    k5_qkv<<<8192, 64, 0, stream>>>(wq, wk, wv, ws + OFF_S2, ws + OFF_COV, ws + OFF_LQKV);
    k6_attn<<<1024, 256, 0, stream>>>(ws + OFF_LQKV, ws + OFF_COV /* mixed reuses cov region */);
    k7_post<<<2731, 64, 0, stream>>>(ws + OFF_COV, ws + OFF_FEAT);
    k8_lin<<<1024, 256, 0, stream>>>(ws + OFF_FEAT, w_lin, b_lin, out);
}

// Round 3
// 1897.882 us; speedup vs baseline: 1.1664x; 1.1664x over previous
//
#include <hip/hip_runtime.h>
#include <math.h>

// ---------------- problem constants ----------------
constexpr int NSWEEP = 6;   // 8 passed at absmax 0.0078 (roundoff-dominated); 6 keeps margin

// ws offsets (in floats)
constexpr size_t OFF_SUMX   = 0;        // 22
constexpr size_t OFF_G      = 22;       // 253
constexpr size_t OFF_SUM2   = 288;      // 20
constexpr size_t OFF_SUMSQ2 = 308;      // 20
constexpr size_t OFF_S2     = 328;      // 20
constexpr size_t OFF_A      = 352;      // 484
constexpr size_t OFF_D      = 840;      // 22
constexpr size_t OFF_WR     = 864;      // 5280 -> 6144
constexpr size_t OFF_COV    = 6144;     // 8192*400 (later reused as `mixed` 8192*324)
constexpr size_t OFF_LQKV   = 3282944;  // 8192*3*324
constexpr size_t OFF_FEAT   = 11245568; // 1024*1368

// ---------------- constexpr tables ----------------
struct Tri { int a[253]; int b[253]; };
constexpr Tri mk_tri(int n) {
    Tri t{}; int c = 0;
    for (int i = 0; i < n; ++i) for (int j = i; j < n; ++j) { t.a[c] = i; t.b[c] = j; ++c; }
    return t;
}
constexpr Tri T22 = mk_tri(22);
constexpr Tri T20 = mk_tri(20);
constexpr Tri T18 = mk_tri(18);

// round-robin (circle method) schedule for n=18: 17 rounds x 9 disjoint pairs, p<q
struct Sched { int p[17][9]; int q[17][9]; };
constexpr Sched mk_sched() {
    Sched s{};
    for (int r = 0; r < 17; ++r)
        for (int k = 0; k < 9; ++k) {
            int x, y;
            if (k == 0) { x = 17; y = r; }
            else { x = (r + k) % 17; y = (r - k + 17) % 17; }
            s.p[r][k] = x < y ? x : y;
            s.q[r][k] = x < y ? y : x;
        }
    return s;
}
constexpr Sched SCH = mk_sched();

// ---------------- wave-parallel 18x18 Jacobi eigh ----------------
// Lane = base + jj holds column jj (a[i] = A[i][jj]). 3 matrices per wave
// (bases 0,18,36); lanes 54..63 run an isolated garbage duplicate (shfl only
// pulls, so garbage never contaminates groups 0-2).
//
// CORRECTNESS INVARIANT (round-2 bug): every lane of a pair must apply the
// bitwise-IDENTICAL (c,s) in BOTH the row update and the column update.
// Otherwise each round applies J_row^T A J_col with J_row != J_col — not a
// similarity transform — and eigenvalue drift destroys log(lambda_min).
// Here each lane computes a candidate rotation, but ALL uses go through a
// broadcast from the pair's p-lane.
__device__ __forceinline__ float jacobi18(float* __restrict__ a, float* __restrict__ v,
                                          int jj, int base) {
    // per-round partner table (depends only on (r, jj)) — compute once
    int pt[17];
#pragma unroll
    for (int r = 0; r < 17; ++r) {
        int k1 = jj - r; if (k1 < 0) k1 += 17;
        int partner;
        if (jj == 17)      { partner = r; }
        else if (k1 == 0)  { partner = 17; }
        else if (k1 <= 8)  { partner = r - k1; if (partner < 0) partner += 17; }
        else               { partner = r + 17 - k1; if (partner >= 17) partner -= 17; }
        pt[r] = partner;
    }
    // own diagonal, maintained analytically (used only for rotation decisions;
    // final eigenvalue is read from the true stored a[jj])
    float mydiag = a[0];
#pragma unroll
    for (int i = 1; i < 18; ++i) if (jj == i) mydiag = a[i];

    for (int sw = 0; sw < NSWEEP; ++sw) {
#pragma unroll
        for (int r = 0; r < 17; ++r) {
            const int partner = pt[r];
            const int paddr = base + partner;
            const bool isp = jj < partner;
            // partner's diagonal (1 shfl)
            float pd = __shfl(mydiag, paddr, 64);
            // own off-diagonal apq = a[partner] (18-way select, partner lane-varying)
            float apq = a[0];
#pragma unroll
            for (int i = 1; i < 18; ++i) if (partner == i) apq = a[i];
            float app = isp ? mydiag : pd;
            float aqq = isp ? pd : mydiag;
            // candidate rotation (only the p-lane's version will be used)
            float apqc = (fabsf(apq) < 1e-36f) ? 1e-36f : apq;
            float tau = (aqq - app) * 0.5f * __builtin_amdgcn_rcpf(apqc);
            float t0 = __builtin_amdgcn_rcpf(fabsf(tau) + __builtin_amdgcn_sqrtf(1.f + tau * tau));
            t0 = (tau < 0.f) ? -t0 : t0;
            float c0 = __builtin_amdgcn_rsqf(1.f + t0 * t0);
            float s0 = t0 * c0;
            // own pair's UNIFORM rotation: pull from the p-lane (lane-varying bpermute)
            int pmin = base + (isp ? jj : partner);
            float mc = __shfl(c0, pmin, 64);
            float ms = __shfl(s0, pmin, 64);
            float mt = __shfl(t0, pmin, 64);
            // all 9 pair rotations from p-lanes (compile-time addresses) for row update
            float cc[9], ss[9];
#pragma unroll
            for (int k = 0; k < 9; ++k) {
                cc[k] = __shfl(c0, base + SCH.p[r][k], 64);
                ss[k] = __shfl(s0, base + SCH.p[r][k], 64);
            }
            // analytic diagonal update with the APPLIED rotation's t:
            // A'pp = app - t*apq ; A'qq = aqq + t*apq
            mydiag = fmaf(isp ? -mt : mt, apq, mydiag);
            // row update (lane-local registers), all 9 disjoint pairs
#pragma unroll
            for (int k = 0; k < 9; ++k) {
                const int p = SCH.p[r][k], q = SCH.q[r][k];
                float tp = a[p], tq = a[q];
                a[p] = cc[k] * tp - ss[k] * tq;
                a[q] = ss[k] * tp + cc[k] * tq;
            }
            // column update with the SAME uniform (mc,ms) via partner exchange
            float ssig = isp ? -ms : ms;
#pragma unroll
            for (int i = 0; i < 18; ++i) {
                float oa = __shfl(a[i], paddr, 64);
                a[i] = mc * a[i] + ssig * oa;
            }
#pragma unroll
            for (int i = 0; i < 18; ++i) {
                float ov = __shfl(v[i], paddr, 64);
                v[i] = mc * v[i] + ssig * ov;
            }
        }
    }
    // eigenvalue = true stored diagonal (no analytic drift)
    float lam = a[0];
#pragma unroll
    for (int i = 1; i < 18; ++i) if (jj == i) lam = a[i];
    return lam;
}

// ---------------- K0: zero atomic accumulators ----------------
__global__ void k0_zero(float* ws) {
    int tid = threadIdx.x;
    for (int i = tid; i < 352; i += 256) ws[i] = 0.f;
}

// ---------------- K1: x channel sums + Gram (for analytic BN1) ----------------
__global__ __launch_bounds__(256) void k1_stats(const float* __restrict__ x,
                                                float* __restrict__ sumx,
                                                float* __restrict__ G) {
    int b = blockIdx.x, tid = threadIdx.x;
    __shared__ float xt[22 * 257];
    float accp = 0.f, accs = 0.f;
    int c1 = 0, c2 = 0;
    if (tid < 253) { c1 = T22.a[tid]; c2 = T22.b[tid]; }
    const float* xb = x + (size_t)b * 22 * 2047;
    for (int t0 = 0; t0 < 2047; t0 += 256) {
        __syncthreads();
        for (int idx = tid; idx < 22 * 256; idx += 256) {
            int c = idx >> 8, tl = idx & 255;
            int t = t0 + tl;
            xt[c * 257 + tl] = (t < 2047) ? xb[c * 2047 + t] : 0.f;
        }
        __syncthreads();
        if (tid < 253) {
            float s = 0.f;
            for (int t = 0; t < 256; ++t) s += xt[c1 * 257 + t] * xt[c2 * 257 + t];
            accp += s;
        }
        if (tid < 22) {
            float s = 0.f;
            for (int t = 0; t < 256; ++t) s += xt[tid * 257 + t];
            accs += s;
        }
    }
    if (tid < 253) atomicAdd(&G[tid], accp);
    if (tid < 22) atomicAdd(&sumx[tid], accs);
}

// ---------------- K2: finalize BN1 -> A = diag(s1)W, d; reorder w_temp ----------------
__global__ __launch_bounds__(256) void k2_prep(const float* __restrict__ w_spat,
                                               const float* __restrict__ b_spat,
                                               const float* __restrict__ g1,
                                               const float* __restrict__ be1,
                                               const float* __restrict__ w_temp,
                                               const float* __restrict__ sumx,
                                               const float* __restrict__ G,
                                               float* __restrict__ A,
                                               float* __restrict__ dv,
                                               float* __restrict__ w_r) {
    int tid = threadIdx.x;
    __shared__ float cov[22 * 22], mux[22], mu1s[22], s1s[22];
    const float invN = 1.f / (1024.f * 2047.f);
    if (tid < 22) mux[tid] = sumx[tid] * invN;
    __syncthreads();
    if (tid < 253) {
        int c1 = T22.a[tid], c2 = T22.b[tid];
        float cv = G[tid] * invN - mux[c1] * mux[c2];
        cov[c1 * 22 + c2] = cv; cov[c2 * 22 + c1] = cv;
    }
    __syncthreads();
    if (tid < 22) {
        int c = tid;
        float m = b_spat[c], varv = 0.f;
        for (int e = 0; e < 22; ++e) m += w_spat[c * 22 + e] * mux[e];
        for (int i = 0; i < 22; ++i) {
            float wi = w_spat[c * 22 + i];
            for (int j = 0; j < 22; ++j) varv += wi * w_spat[c * 22 + j] * cov[i * 22 + j];
        }
        mu1s[c] = m;
        s1s[c] = g1[c] * rsqrtf(varv + 1e-5f);
    }
    __syncthreads();
    for (int idx = tid; idx < 484; idx += 256) {
        int c = idx / 22;
        A[idx] = s1s[c] * w_spat[idx];
    }
    if (tid < 22) dv[tid] = s1s[tid] * (b_spat[tid] - mu1s[tid]) + be1[tid];
    // w_r[(c*12+k)*20 + f] = w_temp[f][c][k]
    for (int idx = tid; idx < 5280; idx += 256) {
        int f = idx / 264, r = idx % 264;
        w_r[r * 20 + f] = w_temp[idx];
    }
}

// ---------------- K3: fused (spatial+BN1) -> temporal conv -> patch raw cov + BN2 stats ----------------
__global__ __launch_bounds__(256) void k3_conv(const float* __restrict__ x,
                                               const float* __restrict__ wsA,
                                               const float* __restrict__ wsd,
                                               const float* __restrict__ w_r,
                                               float* __restrict__ cov_raw,
                                               float* __restrict__ sum2,
                                               float* __restrict__ sumsq2) {
    int bp = blockIdx.x;           // b*8 + p
    int b = bp >> 3, p = bp & 7;
    int tid = threadIdx.x;
    __shared__ float xs[22 * 267];  // x tile, then conv-input (A x + d, zero-padded) in place
    __shared__ float h2[20 * 257];  // conv output tile (b_temp dropped: shift-invariant)
    __shared__ float pm[20];

    const float* xb = x + (size_t)b * 22 * 2047;
    const int t0 = p * 256 - 6;
    for (int idx = tid; idx < 22 * 267; idx += 256) {
        int c = idx / 267, tl = idx % 267;
        int t = t0 + tl;
        xs[idx] = (t >= 0 && t < 2047) ? xb[c * 2047 + t] : 0.f;
    }
    __syncthreads();
    // conv input in place: column per thread
    for (int tl = tid; tl < 267; tl += 256) {
        float xv[22];
#pragma unroll
        for (int c = 0; c < 22; ++c) xv[c] = xs[c * 267 + tl];
        int t = t0 + tl;
        bool valid = (t >= 0 && t < 2047);
#pragma unroll
        for (int c = 0; c < 22; ++c) {
            float acc = wsd[c];
#pragma unroll
            for (int e = 0; e < 22; ++e) acc += wsA[c * 22 + e] * xv[e];
            xs[c * 267 + tl] = valid ? acc : 0.f;
        }
    }
    __syncthreads();
    // temporal conv: thread = output column
    {
        int tl = tid;
        float acc[20];
#pragma unroll
        for (int f = 0; f < 20; ++f) acc[f] = 0.f;
        for (int c = 0; c < 22; ++c) {
#pragma unroll
            for (int k = 0; k < 12; ++k) {
                float hv = xs[c * 267 + tl + k];
                const float* wp = w_r + (c * 12 + k) * 20;   // wave-uniform -> s_load
#pragma unroll
                for (int f = 0; f < 20; ++f) acc[f] += wp[f] * hv;
            }
        }
#pragma unroll
        for (int f = 0; f < 20; ++f) h2[f * 257 + tl] = acc[f];
    }
    __syncthreads();
    // per-patch means + global BN2 accumulators
    if (tid < 20) {
        int f = tid;
        float s = 0.f, ss = 0.f;
        for (int t = 0; t < 256; ++t) { float v = h2[f * 257 + t]; s += v; ss += v * v; }
        pm[f] = s * (1.f / 256.f);
        atomicAdd(&sum2[f], s);
        atomicAdd(&sumsq2[f], ss);
    }
    __syncthreads();
    // raw patch covariance (unnormalized; trace-norm cancels divisors downstream)
    for (int pr = tid; pr < 210; pr += 256) {
        int f = T20.a[pr], g = T20.b[pr];
        float s = 0.f;
        for (int t = 0; t < 256; ++t) s += h2[f * 257 + t] * h2[g * 257 + t];
        float cv = s - 256.f * pm[f] * pm[g];
        cov_raw[(size_t)bp * 400 + f * 20 + g] = cv;
        if (f != g) cov_raw[(size_t)bp * 400 + g * 20 + f] = cv;
    }
}

// ---------------- K4: finalize BN2 scale ----------------
__global__ void k4_s2(const float* __restrict__ g2, const float* __restrict__ sum2,
                      const float* __restrict__ sumsq2, float* __restrict__ s2) {
    int tid = threadIdx.x;
    if (tid < 20) {
        const float invN = 1.f / (1024.f * 2048.f);
        float mu = sum2[tid] * invN;
        float var = sumsq2[tid] * invN - mu * mu;
        s2[tid] = g2[tid] * rsqrtf(var + 1e-5f);
    }
}

// ---------------- K5: BiMap Q/K/V (s2 folded into W), eigh, logm ----------------
__global__ __launch_bounds__(64) void k5_qkv(const float* __restrict__ wq,
                                             const float* __restrict__ wk,
                                             const float* __restrict__ wv,
                                             const float* __restrict__ s2g,
                                             const float* __restrict__ cov_raw,
                                             float* __restrict__ lqkv) {
    int bp = blockIdx.x;
    int lane = threadIdx.x;
    __shared__ float covn[400];     // RAW patch covariance (s2 folded into Wl)
    __shared__ float Wl[1080];      // [m][18][20], pre-scaled by s2[e]
    __shared__ float Vs[972];       // [m][18][18]
    __shared__ float lws[54];
    __shared__ float s2l[20];

    if (lane < 20) s2l[lane] = s2g[lane];
    __syncthreads();
    for (int idx = lane; idx < 1080; idx += 64) {
        int m = idx / 360, rem = idx % 360;
        const float* W = (m == 0) ? wq : (m == 1) ? wk : wv;
        Wl[idx] = W[rem] * s2l[rem % 20];
    }
    for (int idx = lane; idx < 400; idx += 64)
        covn[idx] = cov_raw[(size_t)bp * 400 + idx];
    __syncthreads();

    // trace of s2-scaled cov (broadcast LDS reads, every lane redundantly)
    float tr = 0.f;
#pragma unroll
    for (int f = 0; f < 20; ++f) tr += covn[f * 21] * s2l[f] * s2l[f];
    float trinv = 1.f / tr;

    int grp = lane / 18;
    int jj = lane - grp * 18;
    int m = grp < 3 ? grp : 2;
    int base = grp * 18;
    // Wrow = scaled W_m row jj
    float Wrow[20];
#pragma unroll
    for (int d = 0; d < 20; ++d) Wrow[d] = Wl[m * 360 + jj * 20 + d];
    // u[e] = sum_d covn[e][d] * Wrow[d]  (covn symmetric)
    float u[20];
#pragma unroll
    for (int e = 0; e < 20; ++e) {
        float acc = 0.f;
#pragma unroll
        for (int d = 0; d < 20; ++d) acc += covn[e * 20 + d] * Wrow[d];
        u[e] = acc;
    }
    // a[i] = trinv * sum_e Wl[m][i][e] * u[e]
    float a[18], v[18];
#pragma unroll
    for (int i = 0; i < 18; ++i) {
        float acc = 0.f;
#pragma unroll
        for (int e = 0; e < 20; ++e) acc += Wl[m * 360 + i * 20 + e] * u[e];
        a[i] = acc * trinv;
        v[i] = (i == jj) ? 1.f : 0.f;
    }
    float lam = jacobi18(a, v, jj, base);
    float lw = __logf(fmaxf(lam, 1e-10f));
    if (grp < 3) {
#pragma unroll
        for (int i = 0; i < 18; ++i) Vs[(m * 18 + i) * 18 + jj] = v[i];
        lws[m * 18 + jj] = lw;
    }
    __syncthreads();
    // L = V diag(lw) V^T, write lq/lk/lv
    for (int idx = lane; idx < 972; idx += 64) {
        int m2 = idx / 324, rem = idx % 324, i = rem / 18, jo = rem % 18;
        float acc = 0.f;
#pragma unroll
        for (int kk = 0; kk < 18; ++kk)
            acc += Vs[(m2 * 18 + i) * 18 + kk] * lws[m2 * 18 + kk] * Vs[(m2 * 18 + jo) * 18 + kk];
        lqkv[(size_t)(bp * 3 + m2) * 324 + rem] = acc;
    }
}

// ---------------- K6: log-Euclidean attention -> mixed tangent matrices ----------------
__global__ __launch_bounds__(256) void k6_attn(const float* __restrict__ lqkv,
                                               float* __restrict__ mixed) {
    int b = blockIdx.x, tid = threadIdx.x;
    __shared__ float L[7776];       // [p][m][324]
    __shared__ float sq[8], sk[8], cross[64], prob[64];
    const float* src = lqkv + (size_t)b * 7776;
    for (int idx = tid; idx < 7776; idx += 256) L[idx] = src[idx];
    __syncthreads();
    if (tid < 64) {
        int i = tid >> 3, j = tid & 7;
        const float* fq = &L[(i * 3 + 0) * 324];
        const float* fk = &L[(j * 3 + 1) * 324];
        float cr = 0.f;
        for (int e = 0; e < 324; ++e) cr += fq[e] * fk[e];
        cross[tid] = cr;
    } else if (tid < 72) {
        int i = tid - 64;
        const float* fq = &L[(i * 3 + 0) * 324];
        float s = 0.f;
        for (int e = 0; e < 324; ++e) s += fq[e] * fq[e];
        sq[i] = s;
    } else if (tid < 80) {
        int i = tid - 72;
        const float* fk = &L[(i * 3 + 1) * 324];
        float s = 0.f;
        for (int e = 0; e < 324; ++e) s += fk[e] * fk[e];
        sk[i] = s;
    }
    __syncthreads();
    if (tid < 8) {
        int j = tid;
        float w[8], mx = -1e30f;
        for (int i = 0; i < 8; ++i) {
            float d2 = fmaxf(sq[i] + sk[j] - 2.f * cross[i * 8 + j], 0.0f);
            float en = sqrtf(d2 + 1e-12f);
            w[i] = 1.f / (1.f + log1pf(en));
            mx = fmaxf(mx, w[i]);
        }
        float ssum = 0.f;
        for (int i = 0; i < 8; ++i) { w[i] = __expf(w[i] - mx); ssum += w[i]; }
        float inv = 1.f / ssum;
        for (int i = 0; i < 8; ++i) prob[i * 8 + j] = w[i] * inv;
    }
    __syncthreads();
    float* dst = mixed + (size_t)b * 8 * 324;
    for (int idx = tid; idx < 8 * 324; idx += 256) {
        int j = idx / 324, e = idx % 324;
        float acc = 0.f;
#pragma unroll
        for (int i = 0; i < 8; ++i) acc += prob[i * 8 + j] * L[(i * 3 + 2) * 324 + e];
        dst[idx] = acc;
    }
}

// ---------------- K7: eigh(mixed) -> clamp eigs (expm∘reeig∘logm collapsed) -> triu vec ----------------
__global__ __launch_bounds__(64) void k7_post(const float* __restrict__ mixed,
                                              float* __restrict__ feat) {
    int blk = blockIdx.x;
    int lane = threadIdx.x;
    int grp = lane / 18;
    int jj = lane - grp * 18;
    int m = grp < 3 ? grp : 2;
    int base = grp * 18;
    int mat = blk * 3 + m;
    int matc = mat < 8192 ? mat : 8191;
    __shared__ float Vs[972];
    __shared__ float lws[54];

    const float* src = mixed + (size_t)matc * 324;
    float a[18], v[18];
#pragma unroll
    for (int i = 0; i < 18; ++i) {
        a[i] = src[i * 18 + jj];
        v[i] = (i == jj) ? 1.f : 0.f;
    }
    float lam = jacobi18(a, v, jj, base);
    float lw = fmaxf(lam, -9.210340371976182f);   // ln(1e-4): expm -> reeig -> logm collapsed
    if (grp < 3) {
#pragma unroll
        for (int i = 0; i < 18; ++i) Vs[(m * 18 + i) * 18 + jj] = v[i];
        lws[m * 18 + jj] = lw;
    }
    __syncthreads();
    for (int idx = lane; idx < 513; idx += 64) {
        int m2 = idx / 171, rem = idx % 171;
        int mat2 = blk * 3 + m2;
        if (mat2 >= 8192) continue;
        int i = T18.a[rem], jo = T18.b[rem];
        float acc = 0.f;
#pragma unroll
        for (int kk = 0; kk < 18; ++kk)
            acc += Vs[(m2 * 18 + i) * 18 + kk] * lws[m2 * 18 + kk] * Vs[(m2 * 18 + jo) * 18 + kk];
        float scl = (i == jo) ? 1.f : 1.41421356237309515f;
        int bb = mat2 >> 3, pp = mat2 & 7;
        feat[(size_t)bb * 1368 + pp * 171 + rem] = acc * scl;
    }
}

// ---------------- K8: final linear ----------------
__global__ __launch_bounds__(256) void k8_lin(const float* __restrict__ feat,
                                              const float* __restrict__ w_lin,
                                              const float* __restrict__ b_lin,
                                              float* __restrict__ out) {
    int b = blockIdx.x, tid = threadIdx.x;
    int o = tid >> 6, lane = tid & 63;
    const float* fb = feat + (size_t)b * 1368;
    const float* wo = w_lin + o * 1368;
    float acc = 0.f;
    for (int e = lane; e < 1368; e += 64) acc += fb[e] * wo[e];
    for (int off = 32; off; off >>= 1) acc += __shfl_down(acc, off, 64);
    if (lane == 0) out[b * 4 + o] = acc + b_lin[o];
}

// ---------------- launcher ----------------
extern "C" void kernel_launch(void* const* d_in, const int* in_sizes, int n_in,
                              void* d_out, int out_size, void* d_ws, size_t ws_size,
                              hipStream_t stream) {
    (void)in_sizes; (void)n_in; (void)out_size; (void)ws_size;
    const float* x      = (const float*)d_in[0];
    const float* w_spat = (const float*)d_in[1];
    const float* b_spat = (const float*)d_in[2];
    const float* g1     = (const float*)d_in[3];
    const float* be1    = (const float*)d_in[4];
    const float* w_temp = (const float*)d_in[5];
    // d_in[6] = b_temp : cancels in patch covariance -> unused
    const float* g2     = (const float*)d_in[7];
    // d_in[8] = be2 : cancels -> unused
    const float* wq     = (const float*)d_in[9];
    const float* wk     = (const float*)d_in[10];
    const float* wv     = (const float*)d_in[11];
    const float* w_lin  = (const float*)d_in[12];
    const float* b_lin  = (const float*)d_in[13];
    float* ws  = (float*)d_ws;
    float* out = (float*)d_out;

    k0_zero<<<1, 256, 0, stream>>>(ws);
    k1_stats<<<1024, 256, 0, stream>>>(x, ws + OFF_SUMX, ws + OFF_G);
    k2_prep<<<1, 256, 0, stream>>>(w_spat, b_spat, g1, be1, w_temp,
                                   ws + OFF_SUMX, ws + OFF_G,
                                   ws + OFF_A, ws + OFF_D, ws + OFF_WR);
    k3_conv<<<8192, 256, 0, stream>>>(x, ws + OFF_A, ws + OFF_D, ws + OFF_WR,
                                      ws + OFF_COV, ws + OFF_SUM2, ws + OFF_SUMSQ2);
    k4_s2<<<1, 64, 0, stream>>>(g2, ws + OFF_SUM2, ws + OFF_SUMSQ2, ws + OFF_S2);
    k5_qkv<<<8192, 64, 0, stream>>>(wq, wk, wv, ws + OFF_S2, ws + OFF_COV, ws + OFF_LQKV);
    k6_attn<<<1024, 256, 0, stream>>>(ws + OFF_LQKV, ws + OFF_COV /* mixed reuses cov region */);
    k7_post<<<2731, 64, 0, stream>>>(ws + OFF_COV, ws + OFF_FEAT);
    k8_lin<<<1024, 256, 0, stream>>>(ws + OFF_FEAT, w_lin, b_lin, out);
}

// Round 4
// 1770.711 us; speedup vs baseline: 1.2502x; 1.0718x over previous
//
#include <hip/hip_runtime.h>
#include <math.h>

// ---------------- problem constants ----------------
constexpr int NSWEEP = 6;   // absmax identical at 6 and 8 sweeps (floor-dominated)

// ws offsets (in floats)
constexpr size_t OFF_SUMX   = 0;        // 22
constexpr size_t OFF_G      = 22;       // 253
constexpr size_t OFF_SUM2   = 288;      // 20
constexpr size_t OFF_SUMSQ2 = 308;      // 20
constexpr size_t OFF_S2     = 328;      // 20
constexpr size_t OFF_A      = 352;      // 484
constexpr size_t OFF_D      = 840;      // 22
constexpr size_t OFF_WR     = 864;      // 5280 -> 6144
constexpr size_t OFF_COV    = 6144;     // 8192*400 (later reused as `mixed` 8192*324)
constexpr size_t OFF_LQKV   = 3282944;  // 8192*3*324
constexpr size_t OFF_FEAT   = 11245568; // 1024*1368

// ---------------- constexpr tables ----------------
struct Tri { int a[253]; int b[253]; };
constexpr Tri mk_tri(int n) {
    Tri t{}; int c = 0;
    for (int i = 0; i < n; ++i) for (int j = i; j < n; ++j) { t.a[c] = i; t.b[c] = j; ++c; }
    return t;
}
constexpr Tri T22 = mk_tri(22);
constexpr Tri T20 = mk_tri(20);
constexpr Tri T18 = mk_tri(18);

// round-robin (circle method) schedule for n=18: 17 rounds x 9 disjoint pairs, p<q
struct Sched { int p[17][9]; int q[17][9]; };
constexpr Sched mk_sched() {
    Sched s{};
    for (int r = 0; r < 17; ++r)
        for (int k = 0; k < 9; ++k) {
            int x, y;
            if (k == 0) { x = 17; y = r; }
            else { x = (r + k) % 17; y = (r - k + 17) % 17; }
            s.p[r][k] = x < y ? x : y;
            s.q[r][k] = x < y ? y : x;
        }
    return s;
}
constexpr Sched SCH = mk_sched();

// ---------------- wave-parallel 18x18 Jacobi eigh ----------------
// Lane = base + jj holds column jj (a[i] = A[i][jj]). 3 matrices per wave
// (bases 0,18,36); lanes 54..63 run an isolated garbage duplicate (shfl only
// pulls, so garbage never contaminates groups 0-2).
//
// CORRECTNESS INVARIANT: every lane of a pair must apply the bitwise-IDENTICAL
// (c,s) in BOTH the row and the column update (else not a similarity
// transform; eigenvalue drift destroys log(lambda_min)). Achieved here by
// broadcasting the 9 pair tangents t from the p-lanes and recomputing
// (c,s) = (rsq(1+t^2), t*c) redundantly in every lane — identical inputs +
// identical instruction sequence -> identical bits. This cuts DS traffic
// per round from 58 to 46 ops (LDS pipe is the measured bottleneck).
__device__ __forceinline__ float jacobi18(float* __restrict__ a, float* __restrict__ v,
                                          int jj, int base) {
    // per-round partner table (depends only on (r, jj)) — compute once
    int pt[17];
#pragma unroll
    for (int r = 0; r < 17; ++r) {
        int k1 = jj - r; if (k1 < 0) k1 += 17;
        int partner;
        if (jj == 17)      { partner = r; }
        else if (k1 == 0)  { partner = 17; }
        else if (k1 <= 8)  { partner = r - k1; if (partner < 0) partner += 17; }
        else               { partner = r + 17 - k1; if (partner >= 17) partner -= 17; }
        pt[r] = partner;
    }
    // own pair index kk per round (which of the 9 disjoint pairs this lane is in)
    int kt[17];
#pragma unroll
    for (int r = 0; r < 17; ++r) {
        int k1 = jj - r; if (k1 < 0) k1 += 17;
        kt[r] = (jj == 17) ? 0 : (k1 == 0 ? 0 : (k1 <= 8 ? k1 : 17 - k1));
    }
    // own diagonal, maintained analytically (used only for rotation decisions;
    // final eigenvalue is read from the true stored a[jj])
    float mydiag = a[0];
#pragma unroll
    for (int i = 1; i < 18; ++i) if (jj == i) mydiag = a[i];

    for (int sw = 0; sw < NSWEEP; ++sw) {
#pragma unroll
        for (int r = 0; r < 17; ++r) {
            const int partner = pt[r];
            const int paddr = base + partner;
            const bool isp = jj < partner;
            // partner's diagonal (1 shfl)
            float pd = __shfl(mydiag, paddr, 64);
            // own off-diagonal apq = a[partner] (18-way select, partner lane-varying)
            float apq = a[0];
#pragma unroll
            for (int i = 1; i < 18; ++i) if (partner == i) apq = a[i];
            float app = isp ? mydiag : pd;
            float aqq = isp ? pd : mydiag;
            // candidate tangent (only the p-lane's version gets used)
            float apqc = (fabsf(apq) < 1e-36f) ? 1e-36f : apq;
            float tau = (aqq - app) * 0.5f * __builtin_amdgcn_rcpf(apqc);
            float t0 = __builtin_amdgcn_rcpf(fabsf(tau) + __builtin_amdgcn_sqrtf(1.f + tau * tau));
            t0 = (tau < 0.f) ? -t0 : t0;
            // broadcast the 9 pair tangents from p-lanes (9 DS ops)
            float tb[9];
#pragma unroll
            for (int k = 0; k < 9; ++k)
                tb[k] = __shfl(t0, base + SCH.p[r][k], 64);
            // recompute (c,s) locally — bitwise identical in every lane
            float cc[9], ss[9];
#pragma unroll
            for (int k = 0; k < 9; ++k) {
                cc[k] = __builtin_amdgcn_rsqf(1.f + tb[k] * tb[k]);
                ss[k] = tb[k] * cc[k];
            }
            // own pair's uniform rotation: select from the SAME arrays the
            // row update uses (bitwise consistency row vs column)
            const int kk = kt[r];
            float mt = tb[0], mc = cc[0], ms = ss[0];
#pragma unroll
            for (int t2 = 1; t2 < 9; ++t2)
                if (kk == t2) { mt = tb[t2]; mc = cc[t2]; ms = ss[t2]; }
            // analytic diagonal update: A'pp = app - t*apq ; A'qq = aqq + t*apq
            mydiag = fmaf(isp ? -mt : mt, apq, mydiag);
            // row update (lane-local registers), all 9 disjoint pairs
#pragma unroll
            for (int k = 0; k < 9; ++k) {
                const int p = SCH.p[r][k], q = SCH.q[r][k];
                float tp = a[p], tq = a[q];
                a[p] = cc[k] * tp - ss[k] * tq;
                a[q] = ss[k] * tp + cc[k] * tq;
            }
            // column update with the SAME uniform (mc,ms) via partner exchange
            float ssig = isp ? -ms : ms;
#pragma unroll
            for (int i = 0; i < 18; ++i) {
                float oa = __shfl(a[i], paddr, 64);
                a[i] = mc * a[i] + ssig * oa;
            }
#pragma unroll
            for (int i = 0; i < 18; ++i) {
                float ov = __shfl(v[i], paddr, 64);
                v[i] = mc * v[i] + ssig * ov;
            }
        }
    }
    // eigenvalue = true stored diagonal (no analytic drift)
    float lam = a[0];
#pragma unroll
    for (int i = 1; i < 18; ++i) if (jj == i) lam = a[i];
    return lam;
}

// ---------------- K0: zero atomic accumulators ----------------
__global__ void k0_zero(float* ws) {
    int tid = threadIdx.x;
    for (int i = tid; i < 352; i += 256) ws[i] = 0.f;
}

// ---------------- K1: x channel sums + Gram (for analytic BN1) ----------------
__global__ __launch_bounds__(256) void k1_stats(const float* __restrict__ x,
                                                float* __restrict__ sumx,
                                                float* __restrict__ G) {
    int b = blockIdx.x, tid = threadIdx.x;
    __shared__ float xt[22 * 257];
    float accp = 0.f, accs = 0.f;
    int c1 = 0, c2 = 0;
    if (tid < 253) { c1 = T22.a[tid]; c2 = T22.b[tid]; }
    const float* xb = x + (size_t)b * 22 * 2047;
    for (int t0 = 0; t0 < 2047; t0 += 256) {
        __syncthreads();
        for (int idx = tid; idx < 22 * 256; idx += 256) {
            int c = idx >> 8, tl = idx & 255;
            int t = t0 + tl;
            xt[c * 257 + tl] = (t < 2047) ? xb[c * 2047 + t] : 0.f;
        }
        __syncthreads();
        if (tid < 253) {
            float s = 0.f;
            for (int t = 0; t < 256; ++t) s += xt[c1 * 257 + t] * xt[c2 * 257 + t];
            accp += s;
        }
        if (tid < 22) {
            float s = 0.f;
            for (int t = 0; t < 256; ++t) s += xt[tid * 257 + t];
            accs += s;
        }
    }
    if (tid < 253) atomicAdd(&G[tid], accp);
    if (tid < 22) atomicAdd(&sumx[tid], accs);
}

// ---------------- K2: finalize BN1 -> A = diag(s1)W, d; reorder w_temp ----------------
__global__ __launch_bounds__(256) void k2_prep(const float* __restrict__ w_spat,
                                               const float* __restrict__ b_spat,
                                               const float* __restrict__ g1,
                                               const float* __restrict__ be1,
                                               const float* __restrict__ w_temp,
                                               const float* __restrict__ sumx,
                                               const float* __restrict__ G,
                                               float* __restrict__ A,
                                               float* __restrict__ dv,
                                               float* __restrict__ w_r) {
    int tid = threadIdx.x;
    __shared__ float cov[22 * 22], mux[22], mu1s[22], s1s[22];
    const float invN = 1.f / (1024.f * 2047.f);
    if (tid < 22) mux[tid] = sumx[tid] * invN;
    __syncthreads();
    if (tid < 253) {
        int c1 = T22.a[tid], c2 = T22.b[tid];
        float cv = G[tid] * invN - mux[c1] * mux[c2];
        cov[c1 * 22 + c2] = cv; cov[c2 * 22 + c1] = cv;
    }
    __syncthreads();
    if (tid < 22) {
        int c = tid;
        float m = b_spat[c], varv = 0.f;
        for (int e = 0; e < 22; ++e) m += w_spat[c * 22 + e] * mux[e];
        for (int i = 0; i < 22; ++i) {
            float wi = w_spat[c * 22 + i];
            for (int j = 0; j < 22; ++j) varv += wi * w_spat[c * 22 + j] * cov[i * 22 + j];
        }
        mu1s[c] = m;
        s1s[c] = g1[c] * rsqrtf(varv + 1e-5f);
    }
    __syncthreads();
    for (int idx = tid; idx < 484; idx += 256) {
        int c = idx / 22;
        A[idx] = s1s[c] * w_spat[idx];
    }
    if (tid < 22) dv[tid] = s1s[tid] * (b_spat[tid] - mu1s[tid]) + be1[tid];
    // w_r[(c*12+k)*20 + f] = w_temp[f][c][k]
    for (int idx = tid; idx < 5280; idx += 256) {
        int f = idx / 264, r = idx % 264;
        w_r[r * 20 + f] = w_temp[idx];
    }
}

// ---------------- K3: fused (spatial+BN1) -> temporal conv -> patch raw cov + BN2 stats ----------------
__global__ __launch_bounds__(256) void k3_conv(const float* __restrict__ x,
                                               const float* __restrict__ wsA,
                                               const float* __restrict__ wsd,
                                               const float* __restrict__ w_r,
                                               float* __restrict__ cov_raw,
                                               float* __restrict__ sum2,
                                               float* __restrict__ sumsq2) {
    int bp = blockIdx.x;           // b*8 + p
    int b = bp >> 3, p = bp & 7;
    int tid = threadIdx.x;
    __shared__ float xs[22 * 267];  // x tile, then conv-input (A x + d, zero-padded) in place
    __shared__ float h2[20 * 257];  // conv output tile (b_temp dropped: shift-invariant)
    __shared__ float pm[20];

    const float* xb = x + (size_t)b * 22 * 2047;
    const int t0 = p * 256 - 6;
    for (int idx = tid; idx < 22 * 267; idx += 256) {
        int c = idx / 267, tl = idx % 267;
        int t = t0 + tl;
        xs[idx] = (t >= 0 && t < 2047) ? xb[c * 2047 + t] : 0.f;
    }
    __syncthreads();
    // conv input in place: column per thread
    for (int tl = tid; tl < 267; tl += 256) {
        float xv[22];
#pragma unroll
        for (int c = 0; c < 22; ++c) xv[c] = xs[c * 267 + tl];
        int t = t0 + tl;
        bool valid = (t >= 0 && t < 2047);
#pragma unroll
        for (int c = 0; c < 22; ++c) {
            float acc = wsd[c];
#pragma unroll
            for (int e = 0; e < 22; ++e) acc += wsA[c * 22 + e] * xv[e];
            xs[c * 267 + tl] = valid ? acc : 0.f;
        }
    }
    __syncthreads();
    // temporal conv: thread = output column
    {
        int tl = tid;
        float acc[20];
#pragma unroll
        for (int f = 0; f < 20; ++f) acc[f] = 0.f;
        for (int c = 0; c < 22; ++c) {
#pragma unroll
            for (int k = 0; k < 12; ++k) {
                float hv = xs[c * 267 + tl + k];
                const float* wp = w_r + (c * 12 + k) * 20;   // wave-uniform -> s_load
#pragma unroll
                for (int f = 0; f < 20; ++f) acc[f] += wp[f] * hv;
            }
        }
#pragma unroll
        for (int f = 0; f < 20; ++f) h2[f * 257 + tl] = acc[f];
    }
    __syncthreads();
    // per-patch means + global BN2 accumulators
    if (tid < 20) {
        int f = tid;
        float s = 0.f, ss = 0.f;
        for (int t = 0; t < 256; ++t) { float v = h2[f * 257 + t]; s += v; ss += v * v; }
        pm[f] = s * (1.f / 256.f);
        atomicAdd(&sum2[f], s);
        atomicAdd(&sumsq2[f], ss);
    }
    __syncthreads();
    // raw patch covariance (unnormalized; trace-norm cancels divisors downstream)
    for (int pr = tid; pr < 210; pr += 256) {
        int f = T20.a[pr], g = T20.b[pr];
        float s = 0.f;
        for (int t = 0; t < 256; ++t) s += h2[f * 257 + t] * h2[g * 257 + t];
        float cv = s - 256.f * pm[f] * pm[g];
        cov_raw[(size_t)bp * 400 + f * 20 + g] = cv;
        if (f != g) cov_raw[(size_t)bp * 400 + g * 20 + f] = cv;
    }
}

// ---------------- K4: finalize BN2 scale ----------------
__global__ void k4_s2(const float* __restrict__ g2, const float* __restrict__ sum2,
                      const float* __restrict__ sumsq2, float* __restrict__ s2) {
    int tid = threadIdx.x;
    if (tid < 20) {
        const float invN = 1.f / (1024.f * 2048.f);
        float mu = sum2[tid] * invN;
        float var = sumsq2[tid] * invN - mu * mu;
        s2[tid] = g2[tid] * rsqrtf(var + 1e-5f);
    }
}

// ---------------- K5: BiMap Q/K/V (s2 folded into W), eigh, logm ----------------
__global__ __launch_bounds__(64) void k5_qkv(const float* __restrict__ wq,
                                             const float* __restrict__ wk,
                                             const float* __restrict__ wv,
                                             const float* __restrict__ s2g,
                                             const float* __restrict__ cov_raw,
                                             float* __restrict__ lqkv) {
    int bp = blockIdx.x;
    int lane = threadIdx.x;
    __shared__ float covn[400];     // RAW patch covariance (s2 folded into Wl)
    __shared__ float Wl[1080];      // [m][18][20], pre-scaled by s2[e]
    __shared__ float Vs[972];       // [m][18][18]
    __shared__ float lws[54];
    __shared__ float s2l[20];

    if (lane < 20) s2l[lane] = s2g[lane];
    __syncthreads();
    for (int idx = lane; idx < 1080; idx += 64) {
        int m = idx / 360, rem = idx % 360;
        const float* W = (m == 0) ? wq : (m == 1) ? wk : wv;
        Wl[idx] = W[rem] * s2l[rem % 20];
    }
    for (int idx = lane; idx < 400; idx += 64)
        covn[idx] = cov_raw[(size_t)bp * 400 + idx];
    __syncthreads();

    // trace of s2-scaled cov (broadcast LDS reads, every lane redundantly)
    float tr = 0.f;
#pragma unroll
    for (int f = 0; f < 20; ++f) tr += covn[f * 21] * s2l[f] * s2l[f];
    float trinv = 1.f / tr;

    int grp = lane / 18;
    int jj = lane - grp * 18;
    int m = grp < 3 ? grp : 2;
    int base = grp * 18;
    // Wrow = scaled W_m row jj
    float Wrow[20];
#pragma unroll
    for (int d = 0; d < 20; ++d) Wrow[d] = Wl[m * 360 + jj * 20 + d];
    // u[e] = sum_d covn[e][d] * Wrow[d]  (covn symmetric)
    float u[20];
#pragma unroll
    for (int e = 0; e < 20; ++e) {
        float acc = 0.f;
#pragma unroll
        for (int d = 0; d < 20; ++d) acc += covn[e * 20 + d] * Wrow[d];
        u[e] = acc;
    }
    // a[i] = trinv * sum_e Wl[m][i][e] * u[e]
    float a[18], v[18];
#pragma unroll
    for (int i = 0; i < 18; ++i) {
        float acc = 0.f;
#pragma unroll
        for (int e = 0; e < 20; ++e) acc += Wl[m * 360 + i * 20 + e] * u[e];
        a[i] = acc * trinv;
        v[i] = (i == jj) ? 1.f : 0.f;
    }
    float lam = jacobi18(a, v, jj, base);
    float lw = __logf(fmaxf(lam, 1e-10f));
    if (grp < 3) {
#pragma unroll
        for (int i = 0; i < 18; ++i) Vs[(m * 18 + i) * 18 + jj] = v[i];
        lws[m * 18 + jj] = lw;
    }
    __syncthreads();
    // L = V diag(lw) V^T, write lq/lk/lv
    for (int idx = lane; idx < 972; idx += 64) {
        int m2 = idx / 324, rem = idx % 324, i = rem / 18, jo = rem % 18;
        float acc = 0.f;
#pragma unroll
        for (int kk = 0; kk < 18; ++kk)
            acc += Vs[(m2 * 18 + i) * 18 + kk] * lws[m2 * 18 + kk] * Vs[(m2 * 18 + jo) * 18 + kk];
        lqkv[(size_t)(bp * 3 + m2) * 324 + rem] = acc;
    }
}

// ---------------- K6: log-Euclidean attention -> mixed tangent matrices ----------------
__global__ __launch_bounds__(256) void k6_attn(const float* __restrict__ lqkv,
                                               float* __restrict__ mixed) {
    int b = blockIdx.x, tid = threadIdx.x;
    __shared__ float L[7776];       // [p][m][324]
    __shared__ float sq[8], sk[8], cross[64], prob[64];
    const float* src = lqkv + (size_t)b * 7776;
    for (int idx = tid; idx < 7776; idx += 256) L[idx] = src[idx];
    __syncthreads();
    if (tid < 64) {
        int i = tid >> 3, j = tid & 7;
        const float* fq = &L[(i * 3 + 0) * 324];
        const float* fk = &L[(j * 3 + 1) * 324];
        float cr = 0.f;
        for (int e = 0; e < 324; ++e) cr += fq[e] * fk[e];
        cross[tid] = cr;
    } else if (tid < 72) {
        int i = tid - 64;
        const float* fq = &L[(i * 3 + 0) * 324];
        float s = 0.f;
        for (int e = 0; e < 324; ++e) s += fq[e] * fq[e];
        sq[i] = s;
    } else if (tid < 80) {
        int i = tid - 72;
        const float* fk = &L[(i * 3 + 1) * 324];
        float s = 0.f;
        for (int e = 0; e < 324; ++e) s += fk[e] * fk[e];
        sk[i] = s;
    }
    __syncthreads();
    if (tid < 8) {
        int j = tid;
        float w[8], mx = -1e30f;
        for (int i = 0; i < 8; ++i) {
            float d2 = fmaxf(sq[i] + sk[j] - 2.f * cross[i * 8 + j], 0.0f);
            float en = sqrtf(d2 + 1e-12f);
            w[i] = 1.f / (1.f + log1pf(en));
            mx = fmaxf(mx, w[i]);
        }
        float ssum = 0.f;
        for (int i = 0; i < 8; ++i) { w[i] = __expf(w[i] - mx); ssum += w[i]; }
        float inv = 1.f / ssum;
        for (int i = 0; i < 8; ++i) prob[i * 8 + j] = w[i] * inv;
    }
    __syncthreads();
    float* dst = mixed + (size_t)b * 8 * 324;
    for (int idx = tid; idx < 8 * 324; idx += 256) {
        int j = idx / 324, e = idx % 324;
        float acc = 0.f;
#pragma unroll
        for (int i = 0; i < 8; ++i) acc += prob[i * 8 + j] * L[(i * 3 + 2) * 324 + e];
        dst[idx] = acc;
    }
}

// ---------------- K7: eigh(mixed) -> clamp eigs -> triu vec, with Gershgorin fast path ----------------
// lt = V max(lambda, ln 1e-4) V^T == M exactly when lambda_min(M) > ln(1e-4).
// Gershgorin column bound: lambda_min >= min_j (M_jj - sum_{i!=j} |M_ij|).
// If ALL 3 matrices in the wave are safely above the clamp, skip Jacobi and
// pass M straight through (exact). Fallback path is the unchanged solver.
__global__ __launch_bounds__(64) void k7_post(const float* __restrict__ mixed,
                                              float* __restrict__ feat) {
    int blk = blockIdx.x;
    int lane = threadIdx.x;
    int grp = lane / 18;
    int jj = lane - grp * 18;
    int m = grp < 3 ? grp : 2;
    int base = grp * 18;
    int mat = blk * 3 + m;
    int matc = mat < 8192 ? mat : 8191;
    __shared__ float Vs[972];
    __shared__ float lws[54];
    __shared__ float gbs[64];
    __shared__ int sflag;

    const float* src = mixed + (size_t)matc * 324;
    float a[18], v[18];
#pragma unroll
    for (int i = 0; i < 18; ++i) {
        a[i] = src[i * 18 + jj];
        v[i] = (i == jj) ? 1.f : 0.f;
    }
    // Gershgorin lower bound for this column: a[jj] - sum_{i!=jj}|a[i]|
    {
        float diag = a[0], asum = 0.f;
#pragma unroll
        for (int i = 0; i < 18; ++i) {
            if (jj == i) diag = a[i];
            asum += fabsf(a[i]);
        }
        gbs[lane] = 2.f * diag - asum;   // diag - (asum - diag)
    }
    __syncthreads();
    if (lane == 0) {
        float mn = 1e30f;
        for (int i = 0; i < 54; ++i) mn = fminf(mn, gbs[i]);
        sflag = (mn > -9.2103f) ? 1 : 0;   // strictly above ln(1e-4): clamp is a no-op
    }
    __syncthreads();
    const bool skipAll = (sflag != 0);     // block-uniform

    if (!skipAll) {
        float lam = jacobi18(a, v, jj, base);
        float lw = fmaxf(lam, -9.210340371976182f);   // ln(1e-4)
        if (grp < 3) {
#pragma unroll
            for (int i = 0; i < 18; ++i) Vs[(m * 18 + i) * 18 + jj] = v[i];
            lws[m * 18 + jj] = lw;
        }
    }
    __syncthreads();
    for (int idx = lane; idx < 513; idx += 64) {
        int m2 = idx / 171, rem = idx % 171;
        int mat2 = blk * 3 + m2;
        if (mat2 >= 8192) continue;
        int i = T18.a[rem], jo = T18.b[rem];
        float acc;
        if (skipAll) {
            acc = mixed[(size_t)mat2 * 324 + i * 18 + jo];   // lt == M exactly
        } else {
            acc = 0.f;
#pragma unroll
            for (int kk = 0; kk < 18; ++kk)
                acc += Vs[(m2 * 18 + i) * 18 + kk] * lws[m2 * 18 + kk] * Vs[(m2 * 18 + jo) * 18 + kk];
        }
        float scl = (i == jo) ? 1.f : 1.41421356237309515f;
        int bb = mat2 >> 3, pp = mat2 & 7;
        feat[(size_t)bb * 1368 + pp * 171 + rem] = acc * scl;
    }
}

// ---------------- K8: final linear ----------------
__global__ __launch_bounds__(256) void k8_lin(const float* __restrict__ feat,
                                              const float* __restrict__ w_lin,
                                              const float* __restrict__ b_lin,
                                              float* __restrict__ out) {
    int b = blockIdx.x, tid = threadIdx.x;
    int o = tid >> 6, lane = tid & 63;
    const float* fb = feat + (size_t)b * 1368;
    const float* wo = w_lin + o * 1368;
    float acc = 0.f;
    for (int e = lane; e < 1368; e += 64) acc += fb[e] * wo[e];
    for (int off = 32; off; off >>= 1) acc += __shfl_down(acc, off, 64);
    if (lane == 0) out[b * 4 + o] = acc + b_lin[o];
}

// ---------------- launcher ----------------
extern "C" void kernel_launch(void* const* d_in, const int* in_sizes, int n_in,
                              void* d_out, int out_size, void* d_ws, size_t ws_size,
                              hipStream_t stream) {
    (void)in_sizes; (void)n_in; (void)out_size; (void)ws_size;
    const float* x      = (const float*)d_in[0];
    const float* w_spat = (const float*)d_in[1];
    const float* b_spat = (const float*)d_in[2];
    const float* g1     = (const float*)d_in[3];
    const float* be1    = (const float*)d_in[4];
    const float* w_temp = (const float*)d_in[5];
    // d_in[6] = b_temp : cancels in patch covariance -> unused
    const float* g2     = (const float*)d_in[7];
    // d_in[8] = be2 : cancels -> unused
    const float* wq     = (const float*)d_in[9];
    const float* wk     = (const float*)d_in[10];
    const float* wv     = (const float*)d_in[11];
    const float* w_lin  = (const float*)d_in[12];
    const float* b_lin  = (const float*)d_in[13];
    float* ws  = (float*)d_ws;
    float* out = (float*)d_out;

    k0_zero<<<1, 256, 0, stream>>>(ws);
    k1_stats<<<1024, 256, 0, stream>>>(x, ws + OFF_SUMX, ws + OFF_G);
    k2_prep<<<1, 256, 0, stream>>>(w_spat, b_spat, g1, be1, w_temp,
                                   ws + OFF_SUMX, ws + OFF_G,
                                   ws + OFF_A, ws + OFF_D, ws + OFF_WR);
    k3_conv<<<8192, 256, 0, stream>>>(x, ws + OFF_A, ws + OFF_D, ws + OFF_WR,
                                      ws + OFF_COV, ws + OFF_SUM2, ws + OFF_SUMSQ2);
    k4_s2<<<1, 64, 0, stream>>>(g2, ws + OFF_SUM2, ws + OFF_SUMSQ2, ws + OFF_S2);
    k5_qkv<<<8192, 64, 0, stream>>>(wq, wk, wv, ws + OFF_S2, ws + OFF_COV, ws + OFF_LQKV);
    k6_attn<<<1024, 256, 0, stream>>>(ws + OFF_LQKV, ws + OFF_COV /* mixed reuses cov region */);
    k7_post<<<2731, 64, 0, stream>>>(ws + OFF_COV, ws + OFF_FEAT);
    k8_lin<<<1024, 256, 0, stream>>>(ws + OFF_FEAT, w_lin, b_lin, out);
}

// Round 5
// 1656.203 us; speedup vs baseline: 1.3366x; 1.0691x over previous
//
#include <hip/hip_runtime.h>
#include <math.h>

// ---------------- problem constants ----------------
constexpr int NSWEEP = 5;   // 6 and 8 gave bit-identical absmax (floor) -> try 5

// ws offsets (in floats)
constexpr size_t OFF_SUMX   = 0;        // 22
constexpr size_t OFF_G      = 22;       // 253
constexpr size_t OFF_SUM2   = 288;      // 20
constexpr size_t OFF_SUMSQ2 = 308;      // 20
constexpr size_t OFF_S2     = 328;      // 20
constexpr size_t OFF_A      = 352;      // 484
constexpr size_t OFF_D      = 840;      // 22
constexpr size_t OFF_WR     = 864;      // 5280 -> 6144
constexpr size_t OFF_COV    = 6144;     // 8192*400 (later reused as `mixed` 8192*324)
constexpr size_t OFF_LQKV   = 3282944;  // 8192*3*324
constexpr size_t OFF_FEAT   = 11245568; // 1024*1368

// ---------------- constexpr tables ----------------
struct Tri { int a[253]; int b[253]; };
constexpr Tri mk_tri(int n) {
    Tri t{}; int c = 0;
    for (int i = 0; i < n; ++i) for (int j = i; j < n; ++j) { t.a[c] = i; t.b[c] = j; ++c; }
    return t;
}
constexpr Tri T22 = mk_tri(22);
constexpr Tri T20 = mk_tri(20);
constexpr Tri T18 = mk_tri(18);

// round-robin (circle method) schedule for n=18: 17 rounds x 9 disjoint pairs, p<q
struct Sched { int p[17][9]; int q[17][9]; };
constexpr Sched mk_sched() {
    Sched s{};
    for (int r = 0; r < 17; ++r)
        for (int k = 0; k < 9; ++k) {
            int x, y;
            if (k == 0) { x = 17; y = r; }
            else { x = (r + k) % 17; y = (r - k + 17) % 17; }
            s.p[r][k] = x < y ? x : y;
            s.q[r][k] = x < y ? y : x;
        }
    return s;
}
constexpr Sched SCH = mk_sched();

// ---------------- wave-parallel 18x18 Jacobi eigh ----------------
// Lane (within wave) = base + jj holds column jj (a[i] = A[i][jj]). 3 matrices
// per wave (bases 0,18,36); lanes 54..63 run an isolated duplicate of group 2
// (shfl only pulls, so they never contaminate groups 0-2).
//
// CORRECTNESS INVARIANT: every lane of a pair must apply the bitwise-IDENTICAL
// (c,s) in BOTH the row and the column update (else not a similarity
// transform; eigenvalue drift destroys log(lambda_min)). Achieved by
// broadcasting the 9 pair tangents t from the p-lanes and recomputing
// (c,s) redundantly in every lane — identical inputs + identical instruction
// sequence -> identical bits.
__device__ __forceinline__ float jacobi18(float* __restrict__ a, float* __restrict__ v,
                                          int jj, int base) {
    // per-round partner table (depends only on (r, jj)) — compute once
    int pt[17];
#pragma unroll
    for (int r = 0; r < 17; ++r) {
        int k1 = jj - r; if (k1 < 0) k1 += 17;
        int partner;
        if (jj == 17)      { partner = r; }
        else if (k1 == 0)  { partner = 17; }
        else if (k1 <= 8)  { partner = r - k1; if (partner < 0) partner += 17; }
        else               { partner = r + 17 - k1; if (partner >= 17) partner -= 17; }
        pt[r] = partner;
    }
    // own pair index kk per round (which of the 9 disjoint pairs this lane is in)
    int kt[17];
#pragma unroll
    for (int r = 0; r < 17; ++r) {
        int k1 = jj - r; if (k1 < 0) k1 += 17;
        kt[r] = (jj == 17) ? 0 : (k1 == 0 ? 0 : (k1 <= 8 ? k1 : 17 - k1));
    }
    // own diagonal, maintained analytically (used only for rotation decisions;
    // final eigenvalue is read from the true stored a[jj])
    float mydiag = a[0];
#pragma unroll
    for (int i = 1; i < 18; ++i) if (jj == i) mydiag = a[i];

    for (int sw = 0; sw < NSWEEP; ++sw) {
#pragma unroll
        for (int r = 0; r < 17; ++r) {
            const int partner = pt[r];
            const int paddr = base + partner;
            const bool isp = jj < partner;
            // partner's diagonal (1 shfl)
            float pd = __shfl(mydiag, paddr, 64);
            // own off-diagonal apq = a[partner] (18-way select, partner lane-varying)
            float apq = a[0];
#pragma unroll
            for (int i = 1; i < 18; ++i) if (partner == i) apq = a[i];
            float app = isp ? mydiag : pd;
            float aqq = isp ? pd : mydiag;
            // candidate tangent (only the p-lane's version gets used)
            float apqc = (fabsf(apq) < 1e-36f) ? 1e-36f : apq;
            float tau = (aqq - app) * 0.5f * __builtin_amdgcn_rcpf(apqc);
            float t0 = __builtin_amdgcn_rcpf(fabsf(tau) + __builtin_amdgcn_sqrtf(1.f + tau * tau));
            t0 = (tau < 0.f) ? -t0 : t0;
            // broadcast the 9 pair tangents from p-lanes (9 DS ops)
            float tb[9];
#pragma unroll
            for (int k = 0; k < 9; ++k)
                tb[k] = __shfl(t0, base + SCH.p[r][k], 64);
            // recompute (c,s) locally — bitwise identical in every lane
            float cc[9], ss[9];
#pragma unroll
            for (int k = 0; k < 9; ++k) {
                cc[k] = __builtin_amdgcn_rsqf(1.f + tb[k] * tb[k]);
                ss[k] = tb[k] * cc[k];
            }
            // own pair's uniform rotation: select from the SAME arrays the
            // row update uses (bitwise consistency row vs column)
            const int kk = kt[r];
            float mt = tb[0], mc = cc[0], ms = ss[0];
#pragma unroll
            for (int t2 = 1; t2 < 9; ++t2)
                if (kk == t2) { mt = tb[t2]; mc = cc[t2]; ms = ss[t2]; }
            // analytic diagonal update: A'pp = app - t*apq ; A'qq = aqq + t*apq
            mydiag = fmaf(isp ? -mt : mt, apq, mydiag);
            // row update (lane-local registers), all 9 disjoint pairs
#pragma unroll
            for (int k = 0; k < 9; ++k) {
                const int p = SCH.p[r][k], q = SCH.q[r][k];
                float tp = a[p], tq = a[q];
                a[p] = cc[k] * tp - ss[k] * tq;
                a[q] = ss[k] * tp + cc[k] * tq;
            }
            // column update with the SAME uniform (mc,ms) via partner exchange
            float ssig = isp ? -ms : ms;
#pragma unroll
            for (int i = 0; i < 18; ++i) {
                float oa = __shfl(a[i], paddr, 64);
                a[i] = mc * a[i] + ssig * oa;
            }
#pragma unroll
            for (int i = 0; i < 18; ++i) {
                float ov = __shfl(v[i], paddr, 64);
                v[i] = mc * v[i] + ssig * ov;
            }
        }
    }
    // eigenvalue = true stored diagonal (no analytic drift)
    float lam = a[0];
#pragma unroll
    for (int i = 1; i < 18; ++i) if (jj == i) lam = a[i];
    return lam;
}

// ---------------- K0: zero atomic accumulators ----------------
__global__ void k0_zero(float* ws) {
    int tid = threadIdx.x;
    for (int i = tid; i < 352; i += 256) ws[i] = 0.f;
}

// ---------------- K1: x channel sums + Gram (for analytic BN1) ----------------
__global__ __launch_bounds__(256) void k1_stats(const float* __restrict__ x,
                                                float* __restrict__ sumx,
                                                float* __restrict__ G) {
    int b = blockIdx.x, tid = threadIdx.x;
    __shared__ float xt[22 * 257];
    float accp = 0.f, accs = 0.f;
    int c1 = 0, c2 = 0;
    if (tid < 253) { c1 = T22.a[tid]; c2 = T22.b[tid]; }
    const float* xb = x + (size_t)b * 22 * 2047;
    for (int t0 = 0; t0 < 2047; t0 += 256) {
        __syncthreads();
        for (int idx = tid; idx < 22 * 256; idx += 256) {
            int c = idx >> 8, tl = idx & 255;
            int t = t0 + tl;
            xt[c * 257 + tl] = (t < 2047) ? xb[c * 2047 + t] : 0.f;
        }
        __syncthreads();
        if (tid < 253) {
            float s = 0.f;
            for (int t = 0; t < 256; ++t) s += xt[c1 * 257 + t] * xt[c2 * 257 + t];
            accp += s;
        }
        if (tid < 22) {
            float s = 0.f;
            for (int t = 0; t < 256; ++t) s += xt[tid * 257 + t];
            accs += s;
        }
    }
    if (tid < 253) atomicAdd(&G[tid], accp);
    if (tid < 22) atomicAdd(&sumx[tid], accs);
}

// ---------------- K2: finalize BN1 -> A = diag(s1)W, d; reorder w_temp ----------------
__global__ __launch_bounds__(256) void k2_prep(const float* __restrict__ w_spat,
                                               const float* __restrict__ b_spat,
                                               const float* __restrict__ g1,
                                               const float* __restrict__ be1,
                                               const float* __restrict__ w_temp,
                                               const float* __restrict__ sumx,
                                               const float* __restrict__ G,
                                               float* __restrict__ A,
                                               float* __restrict__ dv,
                                               float* __restrict__ w_r) {
    int tid = threadIdx.x;
    __shared__ float cov[22 * 22], mux[22], mu1s[22], s1s[22];
    const float invN = 1.f / (1024.f * 2047.f);
    if (tid < 22) mux[tid] = sumx[tid] * invN;
    __syncthreads();
    if (tid < 253) {
        int c1 = T22.a[tid], c2 = T22.b[tid];
        float cv = G[tid] * invN - mux[c1] * mux[c2];
        cov[c1 * 22 + c2] = cv; cov[c2 * 22 + c1] = cv;
    }
    __syncthreads();
    if (tid < 22) {
        int c = tid;
        float m = b_spat[c], varv = 0.f;
        for (int e = 0; e < 22; ++e) m += w_spat[c * 22 + e] * mux[e];
        for (int i = 0; i < 22; ++i) {
            float wi = w_spat[c * 22 + i];
            for (int j = 0; j < 22; ++j) varv += wi * w_spat[c * 22 + j] * cov[i * 22 + j];
        }
        mu1s[c] = m;
        s1s[c] = g1[c] * rsqrtf(varv + 1e-5f);
    }
    __syncthreads();
    for (int idx = tid; idx < 484; idx += 256) {
        int c = idx / 22;
        A[idx] = s1s[c] * w_spat[idx];
    }
    if (tid < 22) dv[tid] = s1s[tid] * (b_spat[tid] - mu1s[tid]) + be1[tid];
    // w_r[(c*12+k)*20 + f] = w_temp[f][c][k]
    for (int idx = tid; idx < 5280; idx += 256) {
        int f = idx / 264, r = idx % 264;
        w_r[r * 20 + f] = w_temp[idx];
    }
}

// ---------------- K3: fused (spatial+BN1) -> temporal conv -> patch raw cov + BN2 stats ----------------
__global__ __launch_bounds__(256) void k3_conv(const float* __restrict__ x,
                                               const float* __restrict__ wsA,
                                               const float* __restrict__ wsd,
                                               const float* __restrict__ w_r,
                                               float* __restrict__ cov_raw,
                                               float* __restrict__ sum2,
                                               float* __restrict__ sumsq2) {
    int bp = blockIdx.x;           // b*8 + p
    int b = bp >> 3, p = bp & 7;
    int tid = threadIdx.x;
    __shared__ float xs[22 * 267];  // x tile, then conv-input (A x + d, zero-padded) in place
    __shared__ float h2[20 * 257];  // conv output tile (b_temp dropped: shift-invariant)
    __shared__ float pm[20];

    const float* xb = x + (size_t)b * 22 * 2047;
    const int t0 = p * 256 - 6;
    for (int idx = tid; idx < 22 * 267; idx += 256) {
        int c = idx / 267, tl = idx % 267;
        int t = t0 + tl;
        xs[idx] = (t >= 0 && t < 2047) ? xb[c * 2047 + t] : 0.f;
    }
    __syncthreads();
    // conv input in place: column per thread
    for (int tl = tid; tl < 267; tl += 256) {
        float xv[22];
#pragma unroll
        for (int c = 0; c < 22; ++c) xv[c] = xs[c * 267 + tl];
        int t = t0 + tl;
        bool valid = (t >= 0 && t < 2047);
#pragma unroll
        for (int c = 0; c < 22; ++c) {
            float acc = wsd[c];
#pragma unroll
            for (int e = 0; e < 22; ++e) acc += wsA[c * 22 + e] * xv[e];
            xs[c * 267 + tl] = valid ? acc : 0.f;
        }
    }
    __syncthreads();
    // temporal conv: thread = output column
    {
        int tl = tid;
        float acc[20];
#pragma unroll
        for (int f = 0; f < 20; ++f) acc[f] = 0.f;
        for (int c = 0; c < 22; ++c) {
#pragma unroll
            for (int k = 0; k < 12; ++k) {
                float hv = xs[c * 267 + tl + k];
                const float* wp = w_r + (c * 12 + k) * 20;   // wave-uniform -> s_load
#pragma unroll
                for (int f = 0; f < 20; ++f) acc[f] += wp[f] * hv;
            }
        }
#pragma unroll
        for (int f = 0; f < 20; ++f) h2[f * 257 + tl] = acc[f];
    }
    __syncthreads();
    // per-patch means + global BN2 accumulators
    if (tid < 20) {
        int f = tid;
        float s = 0.f, ss = 0.f;
        for (int t = 0; t < 256; ++t) { float v = h2[f * 257 + t]; s += v; ss += v * v; }
        pm[f] = s * (1.f / 256.f);
        atomicAdd(&sum2[f], s);
        atomicAdd(&sumsq2[f], ss);
    }
    __syncthreads();
    // raw patch covariance (unnormalized; trace-norm cancels divisors downstream)
    for (int pr = tid; pr < 210; pr += 256) {
        int f = T20.a[pr], g = T20.b[pr];
        float s = 0.f;
        for (int t = 0; t < 256; ++t) s += h2[f * 257 + t] * h2[g * 257 + t];
        float cv = s - 256.f * pm[f] * pm[g];
        cov_raw[(size_t)bp * 400 + f * 20 + g] = cv;
        if (f != g) cov_raw[(size_t)bp * 400 + g * 20 + f] = cv;
    }
}

// ---------------- K4: finalize BN2 scale ----------------
__global__ void k4_s2(const float* __restrict__ g2, const float* __restrict__ sum2,
                      const float* __restrict__ sumsq2, float* __restrict__ s2) {
    int tid = threadIdx.x;
    if (tid < 20) {
        const float invN = 1.f / (1024.f * 2048.f);
        float mu = sum2[tid] * invN;
        float var = sumsq2[tid] * invN - mu * mu;
        s2[tid] = g2[tid] * rsqrtf(var + 1e-5f);
    }
}

// ---------------- K5: BiMap Q/K/V (s2 folded into W), eigh, logm ----------------
// 4 waves per block, one bp per wave (occupancy: 1-wave workgroups were
// WG-slot limited at ~7 waves/CU). Wl/s2l shared; covn/Vs/lws per-wave.
__global__ __launch_bounds__(256) void k5_qkv(const float* __restrict__ wq,
                                              const float* __restrict__ wk,
                                              const float* __restrict__ wv,
                                              const float* __restrict__ s2g,
                                              const float* __restrict__ cov_raw,
                                              float* __restrict__ lqkv) {
    int tid = threadIdx.x;
    int wave = tid >> 6;
    int lane = tid & 63;
    int bp = blockIdx.x * 4 + wave;
    __shared__ float Wl[1080];       // [m][18][20], pre-scaled by s2[e] (shared)
    __shared__ float s2l[20];
    __shared__ float covn[4][400];   // per-wave raw patch covariance
    __shared__ float Vs[4][972];
    __shared__ float lws[4][54];

    if (tid < 20) s2l[tid] = s2g[tid];
    for (int idx = lane; idx < 400; idx += 64)
        covn[wave][idx] = cov_raw[(size_t)bp * 400 + idx];
    __syncthreads();
    for (int idx = tid; idx < 1080; idx += 256) {
        int m = idx / 360, rem = idx % 360;
        const float* W = (m == 0) ? wq : (m == 1) ? wk : wv;
        Wl[idx] = W[rem] * s2l[rem % 20];
    }
    __syncthreads();

    // trace of s2-scaled cov (broadcast LDS reads, every lane redundantly)
    float tr = 0.f;
#pragma unroll
    for (int f = 0; f < 20; ++f) tr += covn[wave][f * 21] * s2l[f] * s2l[f];
    float trinv = 1.f / tr;

    int grp = lane / 18;
    int jj = lane - grp * 18;
    int m = grp < 3 ? grp : 2;
    int base = grp * 18;
    // Wrow = scaled W_m row jj
    float Wrow[20];
#pragma unroll
    for (int d = 0; d < 20; ++d) Wrow[d] = Wl[m * 360 + jj * 20 + d];
    // u[e] = sum_d covn[e][d] * Wrow[d]  (covn symmetric)
    float u[20];
#pragma unroll
    for (int e = 0; e < 20; ++e) {
        float acc = 0.f;
#pragma unroll
        for (int d = 0; d < 20; ++d) acc += covn[wave][e * 20 + d] * Wrow[d];
        u[e] = acc;
    }
    // a[i] = trinv * sum_e Wl[m][i][e] * u[e]
    float a[18], v[18];
#pragma unroll
    for (int i = 0; i < 18; ++i) {
        float acc = 0.f;
#pragma unroll
        for (int e = 0; e < 20; ++e) acc += Wl[m * 360 + i * 20 + e] * u[e];
        a[i] = acc * trinv;
        v[i] = (i == jj) ? 1.f : 0.f;
    }
    float lam = jacobi18(a, v, jj, base);
    float lw = __logf(fmaxf(lam, 1e-10f));
    if (grp < 3) {
#pragma unroll
        for (int i = 0; i < 18; ++i) Vs[wave][(m * 18 + i) * 18 + jj] = v[i];
        lws[wave][m * 18 + jj] = lw;
    }
    __builtin_amdgcn_wave_barrier();   // wave-synchronous LDS: write->read same wave
    // L = V diag(lw) V^T, write lq/lk/lv
    for (int idx = lane; idx < 972; idx += 64) {
        int m2 = idx / 324, rem = idx % 324, i = rem / 18, jo = rem % 18;
        float acc = 0.f;
#pragma unroll
        for (int kk = 0; kk < 18; ++kk)
            acc += Vs[wave][(m2 * 18 + i) * 18 + kk] * lws[wave][m2 * 18 + kk] * Vs[wave][(m2 * 18 + jo) * 18 + kk];
        lqkv[(size_t)(bp * 3 + m2) * 324 + rem] = acc;
    }
}

// ---------------- K6: log-Euclidean attention -> mixed tangent matrices ----------------
__global__ __launch_bounds__(256) void k6_attn(const float* __restrict__ lqkv,
                                               float* __restrict__ mixed) {
    int b = blockIdx.x, tid = threadIdx.x;
    __shared__ float L[7776];       // [p][m][324]
    __shared__ float sq[8], sk[8], cross[64], prob[64];
    const float* src = lqkv + (size_t)b * 7776;
    for (int idx = tid; idx < 7776; idx += 256) L[idx] = src[idx];
    __syncthreads();
    if (tid < 64) {
        int i = tid >> 3, j = tid & 7;
        const float* fq = &L[(i * 3 + 0) * 324];
        const float* fk = &L[(j * 3 + 1) * 324];
        float cr = 0.f;
        for (int e = 0; e < 324; ++e) cr += fq[e] * fk[e];
        cross[tid] = cr;
    } else if (tid < 72) {
        int i = tid - 64;
        const float* fq = &L[(i * 3 + 0) * 324];
        float s = 0.f;
        for (int e = 0; e < 324; ++e) s += fq[e] * fq[e];
        sq[i] = s;
    } else if (tid < 80) {
        int i = tid - 72;
        const float* fk = &L[(i * 3 + 1) * 324];
        float s = 0.f;
        for (int e = 0; e < 324; ++e) s += fk[e] * fk[e];
        sk[i] = s;
    }
    __syncthreads();
    if (tid < 8) {
        int j = tid;
        float w[8], mx = -1e30f;
        for (int i = 0; i < 8; ++i) {
            float d2 = fmaxf(sq[i] + sk[j] - 2.f * cross[i * 8 + j], 0.0f);
            float en = sqrtf(d2 + 1e-12f);
            w[i] = 1.f / (1.f + log1pf(en));
            mx = fmaxf(mx, w[i]);
        }
        float ssum = 0.f;
        for (int i = 0; i < 8; ++i) { w[i] = __expf(w[i] - mx); ssum += w[i]; }
        float inv = 1.f / ssum;
        for (int i = 0; i < 8; ++i) prob[i * 8 + j] = w[i] * inv;
    }
    __syncthreads();
    float* dst = mixed + (size_t)b * 8 * 324;
    for (int idx = tid; idx < 8 * 324; idx += 256) {
        int j = idx / 324, e = idx % 324;
        float acc = 0.f;
#pragma unroll
        for (int i = 0; i < 8; ++i) acc += prob[i * 8 + j] * L[(i * 3 + 2) * 324 + e];
        dst[idx] = acc;
    }
}

// ---------------- K7: eigh(mixed) -> clamp eigs -> triu vec, Gershgorin fast path ----------------
// 4 waves per block, 3 matrices per wave (12 per block). NO __syncthreads:
// all sync is wave-local (shfl reduce + wave-synchronous LDS slices), so the
// per-wave divergent Gershgorin skip is barrier-safe.
__global__ __launch_bounds__(256) void k7_post(const float* __restrict__ mixed,
                                               float* __restrict__ feat) {
    int tid = threadIdx.x;
    int wave = tid >> 6;
    int lane = tid & 63;
    int blk = blockIdx.x;
    int grp = lane / 18;
    int jj = lane - grp * 18;
    int m = grp < 3 ? grp : 2;
    int base = grp * 18;
    int mat = blk * 12 + wave * 3 + m;
    int matc = mat < 8192 ? mat : 8191;
    __shared__ float Vs[4][972];
    __shared__ float lws[4][54];

    const float* src = mixed + (size_t)matc * 324;
    float a[18], v[18];
#pragma unroll
    for (int i = 0; i < 18; ++i) {
        a[i] = src[i * 18 + jj];
        v[i] = (i == jj) ? 1.f : 0.f;
    }
    // Gershgorin lower bound for this column: diag - sum_{i!=jj}|a[i]| = 2*diag - sum|a[i]|
    float diag = a[0], asum = 0.f;
#pragma unroll
    for (int i = 0; i < 18; ++i) {
        if (jj == i) diag = a[i];
        asum += fabsf(a[i]);
    }
    float gb = 2.f * diag - asum;    // lanes 54..63 hold a duplicate of m=2: harmless
    // wave-min butterfly
#pragma unroll
    for (int off = 32; off; off >>= 1) gb = fminf(gb, __shfl_xor(gb, off, 64));
    const bool skipAll = (gb > -9.2103f);   // wave-uniform; clamp is a no-op -> lt == M

    if (!skipAll) {
        float lam = jacobi18(a, v, jj, base);
        float lw = fmaxf(lam, -9.210340371976182f);   // ln(1e-4)
        if (grp < 3) {
#pragma unroll
            for (int i = 0; i < 18; ++i) Vs[wave][(m * 18 + i) * 18 + jj] = v[i];
            lws[wave][m * 18 + jj] = lw;
        }
    }
    __builtin_amdgcn_wave_barrier();   // wave-synchronous LDS slice
    for (int idx = lane; idx < 513; idx += 64) {
        int m2 = idx / 171, rem = idx % 171;
        int mat2 = blk * 12 + wave * 3 + m2;
        if (mat2 >= 8192) continue;
        int i = T18.a[rem], jo = T18.b[rem];
        float acc;
        if (skipAll) {
            acc = mixed[(size_t)mat2 * 324 + i * 18 + jo];   // lt == M exactly
        } else {
            acc = 0.f;
#pragma unroll
            for (int kk = 0; kk < 18; ++kk)
                acc += Vs[wave][(m2 * 18 + i) * 18 + kk] * lws[wave][m2 * 18 + kk] * Vs[wave][(m2 * 18 + jo) * 18 + kk];
        }
        float scl = (i == jo) ? 1.f : 1.41421356237309515f;
        int bb = mat2 >> 3, pp = mat2 & 7;
        feat[(size_t)bb * 1368 + pp * 171 + rem] = acc * scl;
    }
}

// ---------------- K8: final linear ----------------
__global__ __launch_bounds__(256) void k8_lin(const float* __restrict__ feat,
                                              const float* __restrict__ w_lin,
                                              const float* __restrict__ b_lin,
                                              float* __restrict__ out) {
    int b = blockIdx.x, tid = threadIdx.x;
    int o = tid >> 6, lane = tid & 63;
    const float* fb = feat + (size_t)b * 1368;
    const float* wo = w_lin + o * 1368;
    float acc = 0.f;
    for (int e = lane; e < 1368; e += 64) acc += fb[e] * wo[e];
    for (int off = 32; off; off >>= 1) acc += __shfl_down(acc, off, 64);
    if (lane == 0) out[b * 4 + o] = acc + b_lin[o];
}

// ---------------- launcher ----------------
extern "C" void kernel_launch(void* const* d_in, const int* in_sizes, int n_in,
                              void* d_out, int out_size, void* d_ws, size_t ws_size,
                              hipStream_t stream) {
    (void)in_sizes; (void)n_in; (void)out_size; (void)ws_size;
    const float* x      = (const float*)d_in[0];
    const float* w_spat = (const float*)d_in[1];
    const float* b_spat = (const float*)d_in[2];
    const float* g1     = (const float*)d_in[3];
    const float* be1    = (const float*)d_in[4];
    const float* w_temp = (const float*)d_in[5];
    // d_in[6] = b_temp : cancels in patch covariance -> unused
    const float* g2     = (const float*)d_in[7];
    // d_in[8] = be2 : cancels -> unused
    const float* wq     = (const float*)d_in[9];
    const float* wk     = (const float*)d_in[10];
    const float* wv     = (const float*)d_in[11];
    const float* w_lin  = (const float*)d_in[12];
    const float* b_lin  = (const float*)d_in[13];
    float* ws  = (float*)d_ws;
    float* out = (float*)d_out;

    k0_zero<<<1, 256, 0, stream>>>(ws);
    k1_stats<<<1024, 256, 0, stream>>>(x, ws + OFF_SUMX, ws + OFF_G);
    k2_prep<<<1, 256, 0, stream>>>(w_spat, b_spat, g1, be1, w_temp,
                                   ws + OFF_SUMX, ws + OFF_G,
                                   ws + OFF_A, ws + OFF_D, ws + OFF_WR);
    k3_conv<<<8192, 256, 0, stream>>>(x, ws + OFF_A, ws + OFF_D, ws + OFF_WR,
                                      ws + OFF_COV, ws + OFF_SUM2, ws + OFF_SUMSQ2);
    k4_s2<<<1, 64, 0, stream>>>(g2, ws + OFF_SUM2, ws + OFF_SUMSQ2, ws + OFF_S2);
    k5_qkv<<<2048, 256, 0, stream>>>(wq, wk, wv, ws + OFF_S2, ws + OFF_COV, ws + OFF_LQKV);
    k6_attn<<<1024, 256, 0, stream>>>(ws + OFF_LQKV, ws + OFF_COV /* mixed reuses cov region */);
    k7_post<<<683, 256, 0, stream>>>(ws + OFF_COV, ws + OFF_FEAT);
    k8_lin<<<1024, 256, 0, stream>>>(ws + OFF_FEAT, w_lin, b_lin, out);
}